// Round 8
// baseline (607.992 us; speedup 1.0000x reference)
//
#include <hip/hip_runtime.h>
#include <hip/hip_bf16.h>

#define NN    100000
#define NE    1600000
#define INCH  512
#define HIDCH 256
#define OUTCH 32
#define KHOPS 10
#define NEPAD (NE + 3 * NN)

typedef __attribute__((ext_vector_type(8))) short short8;
typedef __attribute__((ext_vector_type(4))) float f32x4;

#define GLOAD_LDS16(gsrc, ldst) \
  __builtin_amdgcn_global_load_lds((const __attribute__((address_space(1))) void*)(gsrc), \
                                   (__attribute__((address_space(3))) void*)(ldst), 16, 0, 0)

// ---------------- workspace layout ----------------
constexpr size_t ws_align(size_t x) { return (x + 255) & ~(size_t)255; }
constexpr size_t USZ = ws_align((size_t)(NN + 1) * 32 * 2);   // U table bf16 [NN+1][32]
constexpr size_t OFF_H1   = 0;                                           // [NN][256] bf16
constexpr size_t OFF_U0   = OFF_H1   + ws_align((size_t)NN*HIDCH*2);     // parity 0
constexpr size_t OFF_U1   = OFF_U0   + USZ;                              // parity 1
constexpr size_t OFF_W1TH = OFF_U1   + USZ;                              // [256][512] bf16
constexpr size_t OFF_W1TL = OFF_W1TH + ws_align((size_t)HIDCH*INCH*2);
constexpr size_t OFF_W2TH = OFF_W1TL + ws_align((size_t)HIDCH*INCH*2);   // [32][256] bf16
constexpr size_t OFF_W2TL = OFF_W2TH + ws_align((size_t)OUTCH*HIDCH*2);
constexpr size_t OFF_DEG  = OFF_W2TL + ws_align((size_t)OUTCH*HIDCH*2);  // [NN] int
constexpr size_t OFF_DIS  = OFF_DEG  + ws_align((size_t)NN*4);           // [NN] f32
constexpr size_t OFF_RP   = OFF_DIS  + ws_align((size_t)NN*4);           // [NN+1] int (deg rounded to 4)
constexpr size_t OFF_CUR  = OFF_RP   + ws_align((size_t)(NN+1)*4);       // [NN] int
constexpr size_t OFF_CSR  = OFF_CUR  + ws_align((size_t)NN*4);           // [NEPAD] int src
constexpr size_t OFF_PART = OFF_CSR  + ws_align((size_t)NEPAD*4);        // [128] int
constexpr size_t OFF_OFFS = OFF_PART + ws_align(512);                    // [128] int

// ---------------- bf16 helpers ----------------
__device__ __forceinline__ unsigned short bf16_rne(float f) {
  unsigned int u = __float_as_uint(f);
  u += 0x7fffu + ((u >> 16) & 1u);
  return (unsigned short)(u >> 16);
}
__device__ __forceinline__ float bf16_to_f32(unsigned short h) {
  return __uint_as_float(((unsigned int)h) << 16);
}
__device__ __forceinline__ float bflo(unsigned int w) {
  return __uint_as_float(w << 16);
}
__device__ __forceinline__ float bfhi(unsigned int w) {
  return __uint_as_float(w & 0xffff0000u);
}

// ---------------- degree ----------------
__global__ __launch_bounds__(256) void k_count_deg(const int* __restrict__ col,
                                                   int* __restrict__ deg) {
  int e = blockIdx.x * 256 + threadIdx.x;
  if (e < NE) atomicAdd(&deg[col[e]], 1);
}

// dis + zero the U pad rows (row NN of each parity table: 16 uints each)
__global__ __launch_bounds__(256) void k_dis(const int* __restrict__ deg,
                                             float* __restrict__ dis,
                                             unsigned short* u0, unsigned short* u1) {
  int v = blockIdx.x * 256 + threadIdx.x;
  if (v < NN) {
    int d = deg[v];
    dis[v] = d > 0 ? rsqrtf((float)d) : 0.0f;
  }
  if (blockIdx.x == 0) {
    int t = threadIdx.x;
    if (t < 16)      ((unsigned int*)u0)[(size_t)NN * 16 + t] = 0;
    else if (t < 32) ((unsigned int*)u1)[(size_t)NN * 16 + (t - 16)] = 0;
  }
}

// ---------------- exclusive scan over deg rounded-up-to-4 ----------------
__global__ __launch_bounds__(256) void k_scan1(const int* __restrict__ deg,
                                               int* __restrict__ rp,
                                               int* __restrict__ part) {
  __shared__ int s[256];
  int b = blockIdx.x, t = threadIdx.x;
  int base = b * 1024 + t * 4;
  int v0 = (base + 0 < NN) ? ((deg[base + 0] + 3) & ~3) : 0;
  int v1 = (base + 1 < NN) ? ((deg[base + 1] + 3) & ~3) : 0;
  int v2 = (base + 2 < NN) ? ((deg[base + 2] + 3) & ~3) : 0;
  int v3 = (base + 3 < NN) ? ((deg[base + 3] + 3) & ~3) : 0;
  int tot = v0 + v1 + v2 + v3;
  s[t] = tot;
  __syncthreads();
  for (int d = 1; d < 256; d <<= 1) {
    int x = (t >= d) ? s[t - d] : 0;
    __syncthreads();
    s[t] += x;
    __syncthreads();
  }
  int excl = s[t] - tot;
  if (t == 255) part[b] = s[255];
  if (base + 0 < NN) rp[base + 0] = excl;
  if (base + 1 < NN) rp[base + 1] = excl + v0;
  if (base + 2 < NN) rp[base + 2] = excl + v0 + v1;
  if (base + 3 < NN) rp[base + 3] = excl + v0 + v1 + v2;
}

__global__ __launch_bounds__(128) void k_scan2(const int* __restrict__ part,
                                               int* __restrict__ offs) {
  __shared__ int s[128];
  int t = threadIdx.x;
  int v = (t < 98) ? part[t] : 0;
  s[t] = v;
  __syncthreads();
  for (int d = 1; d < 128; d <<= 1) {
    int x = (t >= d) ? s[t - d] : 0;
    __syncthreads();
    s[t] += x;
    __syncthreads();
  }
  if (t < 98) offs[t] = s[t] - v;
}

__global__ __launch_bounds__(256) void k_scan3(int* __restrict__ rp,
                                               const int* __restrict__ offs,
                                               const int* __restrict__ part,
                                               int* __restrict__ cur) {
  int b = blockIdx.x, t = threadIdx.x;
  int o = offs[b];
  int base = b * 1024 + t * 4;
#pragma unroll
  for (int j = 0; j < 4; ++j) {
    int i = base + j;
    if (i < NN) {
      int r = rp[i] + o;
      rp[i] = r;
      cur[i] = r;
    }
  }
  if (b == 0 && t == 0) rp[NN] = offs[97] + part[97];
}

// fill CSR src-only
__global__ __launch_bounds__(256) void k_fill(const int* __restrict__ ei,
                                              int* __restrict__ cur,
                                              int* __restrict__ csrc) {
  int e = blockIdx.x * 256 + threadIdx.x;
  if (e < NE) {
    int c = ei[NE + e];
    int p = atomicAdd(&cur[c], 1);
    csrc[p] = ei[e];
  }
}

// pad each node's slots up to rounded length with dummy src = NN (zero row)
__global__ __launch_bounds__(256) void k_pad(const int* __restrict__ cur,
                                             const int* __restrict__ rp,
                                             int* __restrict__ csrc) {
  int v = blockIdx.x * 256 + threadIdx.x;
  if (v < NN) {
    int p = cur[v], e = rp[v + 1];
    for (; p < e; ++p) csrc[p] = NN;
  }
}

// ---------------- split-transpose: dst[n][k] = split(src[k][n]) ----------------
__global__ __launch_bounds__(256) void k_splitT(const float* __restrict__ src,
                                                unsigned short* __restrict__ dh,
                                                unsigned short* __restrict__ dl,
                                                int K, int N) {
  int idx = blockIdx.x * 256 + threadIdx.x;
  if (idx >= K * N) return;
  int n = idx / K, k = idx - n * K;
  float v = src[(size_t)k * N + n];
  unsigned short h = bf16_rne(v);
  dh[idx] = h;
  dl[idx] = bf16_rne(v - bf16_to_f32(h));
}

// ---------------- GEMM1 v2: tile 128Mx128Nx32K, 4 waves, single 24KB buffer -------
// Grid 1564 (2 n-tiles) -> 4-6 resident blocks/CU; cross-block overlap hides the
// vmcnt(0)+barrier drain (m97 mechanism). Wave tile 64x64, 32 MFMA/iter.
__global__ __launch_bounds__(256) void k_gemm1(const float* __restrict__ X,
                                               const unsigned short* __restrict__ W1Th,
                                               const unsigned short* __restrict__ W1Tl,
                                               const float* __restrict__ bias1,
                                               unsigned short* __restrict__ H1bf) {
  __shared__ __align__(16) unsigned short Ah[4096], Bh[4096], Bl[4096];  // 24 KB
  const int t = threadIdx.x;
  const int m0 = blockIdx.x * 128;
  const int n0 = blockIdx.y * 128;
  const int w = t >> 6, lane = t & 63;
  const int wm = w >> 1, wn = w & 1;

  // A staging: thread t -> row t>>1, k-half (t&1)*16 (16 f32 = 4 float4)
  const int arow = t >> 1;
  int axrow = m0 + arow; if (axrow >= NN) axrow = NN - 1;
  const float* aptr = X + (size_t)axrow * INCH + (t & 1) * 16;
  // frag slot: group = arow>>4; kchunk8 = (t&1)*2 (+1); 16B per (row,kchunk8)
  const int aidx0 = (arow >> 4) * 512 + ((arow & 15) + (t & 1) * 32) * 8;
  const int aidx1 = aidx0 + 128;

  // B via global_load_lds: wave w stages n-groups {w, w+4} of Bh and Bl
  const int bko = (lane >> 4) * 8;
  const unsigned short* bs0 = W1Th + (size_t)(n0 + w * 16 + (lane & 15)) * INCH + bko;
  const unsigned short* bs1 = W1Th + (size_t)(n0 + (w + 4) * 16 + (lane & 15)) * INCH + bko;
  const unsigned short* bs2 = W1Tl + (size_t)(n0 + w * 16 + (lane & 15)) * INCH + bko;
  const unsigned short* bs3 = W1Tl + (size_t)(n0 + (w + 4) * 16 + (lane & 15)) * INCH + bko;

  f32x4 acc[4][4] = {};

#pragma unroll 4
  for (int it = 0; it < 16; ++it) {
    const int k0 = it * 32;
    __syncthreads();                 // previous tile's LDS reads complete
    GLOAD_LDS16(bs0 + k0, &Bh[w * 512]);
    GLOAD_LDS16(bs1 + k0, &Bh[(w + 4) * 512]);
    GLOAD_LDS16(bs2 + k0, &Bl[w * 512]);
    GLOAD_LDS16(bs3 + k0, &Bl[(w + 4) * 512]);
    {
      float4 x0 = *(const float4*)(aptr + k0);
      float4 x1 = *(const float4*)(aptr + k0 + 4);
      float4 x2 = *(const float4*)(aptr + k0 + 8);
      float4 x3 = *(const float4*)(aptr + k0 + 12);
      float af[16] = {x0.x, x0.y, x0.z, x0.w, x1.x, x1.y, x1.z, x1.w,
                      x2.x, x2.y, x2.z, x2.w, x3.x, x3.y, x3.z, x3.w};
      short8 a0, a1;
#pragma unroll
      for (int i = 0; i < 8; ++i) {
        unsigned int u = __float_as_uint(af[i]);
        a0[i] = (short)((u + 0x7fffu + ((u >> 16) & 1u)) >> 16);
        unsigned int u2 = __float_as_uint(af[8 + i]);
        a1[i] = (short)((u2 + 0x7fffu + ((u2 >> 16) & 1u)) >> 16);
      }
      *(short8*)&Ah[aidx0] = a0;
      *(short8*)&Ah[aidx1] = a1;
    }
    __syncthreads();                 // drain gloads + A writes (vmcnt0+lgkm0)
    short8 afrag[4];
#pragma unroll
    for (int mf = 0; mf < 4; ++mf)
      afrag[mf] = *(const short8*)&Ah[(wm * 4 + mf) * 512 + lane * 8];
#pragma unroll
    for (int nf = 0; nf < 4; ++nf) {
      short8 bfh = *(const short8*)&Bh[(wn * 4 + nf) * 512 + lane * 8];
      short8 bfl = *(const short8*)&Bl[(wn * 4 + nf) * 512 + lane * 8];
#pragma unroll
      for (int mf = 0; mf < 4; ++mf) {
        acc[mf][nf] = __builtin_amdgcn_mfma_f32_16x16x32_bf16(afrag[mf], bfh, acc[mf][nf], 0, 0, 0);
        acc[mf][nf] = __builtin_amdgcn_mfma_f32_16x16x32_bf16(afrag[mf], bfl, acc[mf][nf], 0, 0, 0);
      }
    }
  }

  // epilogue: +bias, relu, cvt bf16, store
  const int colbase = n0 + wn * 64 + (lane & 15);
  const int rowbase = m0 + wm * 64 + ((lane >> 4) << 2);
#pragma unroll
  for (int nf = 0; nf < 4; ++nf) {
    int col = colbase + nf * 16;
    float b = bias1[col];
#pragma unroll
    for (int mf = 0; mf < 4; ++mf) {
#pragma unroll
      for (int r = 0; r < 4; ++r) {
        int row = rowbase + mf * 16 + r;
        if (row < NN) {
          float h = fmaxf(acc[mf][nf][r] + b, 0.f);
          H1bf[(size_t)row * HIDCH + col] = bf16_rne(h);
        }
      }
    }
  }
}

// ---------------- GEMM2: h = H1bf @ W2 + b2; u0 = bf16(dis*h); out = g0*h ---------
__global__ __launch_bounds__(256) void k_gemm2(const unsigned short* __restrict__ H1bf,
                                               const unsigned short* __restrict__ W2Th,
                                               const unsigned short* __restrict__ W2Tl,
                                               const float* __restrict__ bias2,
                                               const float* __restrict__ gamma,
                                               const float* __restrict__ dis,
                                               unsigned short* __restrict__ u0,
                                               float* __restrict__ out) {
  __shared__ __align__(16) unsigned short A2[8192];
  __shared__ __align__(16) unsigned short B2h[2048], B2l[2048];
  const int t = threadIdx.x;
  const int m0 = blockIdx.x * 128;

  const int arow = t >> 1;
  int axrow = m0 + arow; if (axrow >= NN) axrow = NN - 1;
  const int akb = (t & 1) * 32;
  const unsigned short* ap = H1bf + (size_t)axrow * HIDCH + akb;
  const int abase = ((arow >> 4) * 2 + (akb >> 5)) * 512 + (arow & 15) * 8;

  const int bnr = t >> 3, bkq = (t & 7) * 8;
  const int bslot = ((bnr >> 4) * 2 + (bkq >> 5)) * 512 +
                    ((bnr & 15) + (((bkq & 31) >> 3) << 4)) * 8;
  const unsigned short* bhp = W2Th + (size_t)bnr * HIDCH + bkq;
  const unsigned short* blp = W2Tl + (size_t)bnr * HIDCH + bkq;

  const int w = t >> 6, lane = t & 63;

  f32x4 acc[2][2] = {};

  for (int k0 = 0; k0 < HIDCH; k0 += 64) {
    uint4 a0 = *(const uint4*)(ap + k0);
    uint4 a1 = *(const uint4*)(ap + k0 + 8);
    uint4 a2 = *(const uint4*)(ap + k0 + 16);
    uint4 a3 = *(const uint4*)(ap + k0 + 24);
    uint4 bh = *(const uint4*)(bhp + k0);
    uint4 bl = *(const uint4*)(blp + k0);

    __syncthreads();

    *(uint4*)&A2[abase + 0 * 128] = a0;
    *(uint4*)&A2[abase + 1 * 128] = a1;
    *(uint4*)&A2[abase + 2 * 128] = a2;
    *(uint4*)&A2[abase + 3 * 128] = a3;
    *(uint4*)&B2h[bslot] = bh;
    *(uint4*)&B2l[bslot] = bl;

    __syncthreads();

    const short8* AV  = (const short8*)A2;
    const short8* BHV = (const short8*)B2h;
    const short8* BLV = (const short8*)B2l;
#pragma unroll
    for (int k32 = 0; k32 < 2; ++k32) {
      short8 bfh[2], bfl[2];
#pragma unroll
      for (int nf = 0; nf < 2; ++nf) {
        bfh[nf] = BHV[(nf * 2 + k32) * 64 + lane];
        bfl[nf] = BLV[(nf * 2 + k32) * 64 + lane];
      }
#pragma unroll
      for (int mf = 0; mf < 2; ++mf) {
        short8 a = AV[((w * 2 + mf) * 2 + k32) * 64 + lane];
#pragma unroll
        for (int nf = 0; nf < 2; ++nf) {
          acc[mf][nf] = __builtin_amdgcn_mfma_f32_16x16x32_bf16(a, bfh[nf], acc[mf][nf], 0, 0, 0);
          acc[mf][nf] = __builtin_amdgcn_mfma_f32_16x16x32_bf16(a, bfl[nf], acc[mf][nf], 0, 0, 0);
        }
      }
    }
  }

  const float g0 = gamma[0];
  const int colb = lane & 15;
  const int rowb = m0 + w * 32 + ((lane >> 4) << 2);
  const float b2c0 = bias2[colb], b2c1 = bias2[16 + colb];
#pragma unroll
  for (int mf = 0; mf < 2; ++mf) {
#pragma unroll
    for (int r = 0; r < 4; ++r) {
      int row = rowb + mf * 16 + r;
      if (row < NN) {
        float dv = dis[row];
        float h0 = acc[mf][0][r] + b2c0;
        float h1 = acc[mf][1][r] + b2c1;
        size_t o = (size_t)row * 32 + colb;
        u0[o] = bf16_rne(dv * h0);
        u0[o + 16] = bf16_rne(dv * h1);
        out[o] = g0 * h0;
        out[o + 16] = g0 * h1;
      }
    }
  }
}

// ---------------- hop: full 32-ch rows, 16 lanes/node -----------------------------
// u_k[v] = dis^2[v] * sum_src u_{k-1}[src];  out[v] += gamma_k * dis[v] * sum.
// One edge visit per edge (64B source row = 1 segment). Meta int4 uniform per group.
__global__ __launch_bounds__(256) void k_hop(const unsigned short* __restrict__ Uin,
                                             unsigned short* __restrict__ Uout,
                                             float* __restrict__ out,
                                             const int* __restrict__ rp,
                                             const int* __restrict__ csrc,
                                             const float* __restrict__ dis,
                                             const float* __restrict__ gamma,
                                             int k) {
  const int t = threadIdx.x;
  const int g = t >> 4;                    // node slot 0..15
  const int li = t & 15;                   // lane in group (2 channels)
  const int v = blockIdx.x * 16 + g;
  const int s = rp[v], e = rp[v + 1];      // multiples of 4 (src=NN pads -> zero row)
  const unsigned int* Uin32 = (const unsigned int*)Uin;

  float ax0 = 0.f, ay0 = 0.f, ax1 = 0.f, ay1 = 0.f;
  float ax2 = 0.f, ay2 = 0.f, ax3 = 0.f, ay3 = 0.f;
  int j = s;
  for (; j + 8 <= e; j += 8) {
    int4 sa = *(const int4*)&csrc[j];      // uniform within group -> broadcast
    int4 sb = *(const int4*)&csrc[j + 4];
    unsigned int w0 = Uin32[(size_t)sa.x * 16 + li];
    unsigned int w1 = Uin32[(size_t)sa.y * 16 + li];
    unsigned int w2 = Uin32[(size_t)sa.z * 16 + li];
    unsigned int w3 = Uin32[(size_t)sa.w * 16 + li];
    unsigned int w4 = Uin32[(size_t)sb.x * 16 + li];
    unsigned int w5 = Uin32[(size_t)sb.y * 16 + li];
    unsigned int w6 = Uin32[(size_t)sb.z * 16 + li];
    unsigned int w7 = Uin32[(size_t)sb.w * 16 + li];
    ax0 += bflo(w0); ay0 += bfhi(w0);
    ax1 += bflo(w1); ay1 += bfhi(w1);
    ax2 += bflo(w2); ay2 += bfhi(w2);
    ax3 += bflo(w3); ay3 += bfhi(w3);
    ax0 += bflo(w4); ay0 += bfhi(w4);
    ax1 += bflo(w5); ay1 += bfhi(w5);
    ax2 += bflo(w6); ay2 += bfhi(w6);
    ax3 += bflo(w7); ay3 += bfhi(w7);
  }
  if (j < e) {
    int4 sa = *(const int4*)&csrc[j];
    unsigned int w0 = Uin32[(size_t)sa.x * 16 + li];
    unsigned int w1 = Uin32[(size_t)sa.y * 16 + li];
    unsigned int w2 = Uin32[(size_t)sa.z * 16 + li];
    unsigned int w3 = Uin32[(size_t)sa.w * 16 + li];
    ax0 += bflo(w0); ay0 += bfhi(w0);
    ax1 += bflo(w1); ay1 += bfhi(w1);
    ax2 += bflo(w2); ay2 += bfhi(w2);
    ax3 += bflo(w3); ay3 += bfhi(w3);
  }
  const float Sx = (ax0 + ax1) + (ax2 + ax3);
  const float Sy = (ay0 + ay1) + (ay2 + ay3);
  const float dv = dis[v];
  const float gd = gamma[k] * dv;
  const float d2 = dv * dv;
  unsigned int packed = (unsigned int)bf16_rne(d2 * Sx) |
                        ((unsigned int)bf16_rne(d2 * Sy) << 16);
  ((unsigned int*)Uout)[(size_t)v * 16 + li] = packed;
  const size_t o = (size_t)v * 32 + li * 2;
  float2 po = *(const float2*)&out[o];
  po.x = fmaf(gd, Sx, po.x);
  po.y = fmaf(gd, Sy, po.y);
  *(float2*)&out[o] = po;
}

extern "C" void kernel_launch(void* const* d_in, const int* in_sizes, int n_in,
                              void* d_out, int out_size, void* d_ws, size_t ws_size,
                              hipStream_t stream) {
  const float* x     = (const float*)d_in[0];
  const int*   ei    = (const int*)d_in[1];
  const float* W1    = (const float*)d_in[2];
  const float* b1    = (const float*)d_in[3];
  const float* W2    = (const float*)d_in[4];
  const float* b2    = (const float*)d_in[5];
  const float* gamma = (const float*)d_in[6];
  float* out = (float*)d_out;

  char* ws = (char*)d_ws;
  unsigned short* h1bf = (unsigned short*)(ws + OFF_H1);
  unsigned short* U[2] = {(unsigned short*)(ws + OFF_U0),
                          (unsigned short*)(ws + OFF_U1)};
  unsigned short* w1th = (unsigned short*)(ws + OFF_W1TH);
  unsigned short* w1tl = (unsigned short*)(ws + OFF_W1TL);
  unsigned short* w2th = (unsigned short*)(ws + OFF_W2TH);
  unsigned short* w2tl = (unsigned short*)(ws + OFF_W2TL);
  int*   deg  = (int*)(ws + OFF_DEG);
  float* dis  = (float*)(ws + OFF_DIS);
  int*   rp   = (int*)(ws + OFF_RP);
  int*   cur  = (int*)(ws + OFF_CUR);
  int*   csrc = (int*)(ws + OFF_CSR);
  int*   part = (int*)(ws + OFF_PART);
  int*   offs = (int*)(ws + OFF_OFFS);

  hipMemsetAsync(deg, 0, NN * sizeof(int), stream);

  // weight prep (tiny)
  k_splitT<<<(INCH * HIDCH + 255) / 256, 256, 0, stream>>>(W1, w1th, w1tl, INCH, HIDCH);
  k_splitT<<<(HIDCH * OUTCH + 255) / 256, 256, 0, stream>>>(W2, w2th, w2tl, HIDCH, OUTCH);

  // graph prep
  k_count_deg<<<(NE + 255) / 256, 256, 0, stream>>>(ei + NE, deg);
  k_dis<<<(NN + 255) / 256, 256, 0, stream>>>(deg, dis, U[0], U[1]);
  k_scan1<<<98, 256, 0, stream>>>(deg, rp, part);
  k_scan2<<<1, 128, 0, stream>>>(part, offs);
  k_scan3<<<98, 256, 0, stream>>>(rp, offs, part, cur);
  k_fill<<<(NE + 255) / 256, 256, 0, stream>>>(ei, cur, csrc);
  k_pad<<<(NN + 255) / 256, 256, 0, stream>>>(cur, rp, csrc);

  // MLP
  k_gemm1<<<dim3((NN + 127) / 128, 2), 256, 0, stream>>>(x, w1th, w1tl, b1, h1bf);
  k_gemm2<<<(NN + 127) / 128, 256, 0, stream>>>(h1bf, w2th, w2tl, b2, gamma, dis,
                                                U[0], out);

  // propagation: 10 hops, full 32-ch rows, gamma accumulated straight into out
  for (int k = 1; k <= KHOPS; ++k) {
    k_hop<<<NN / 16, 256, 0, stream>>>(U[(k - 1) & 1], U[k & 1], out,
                                       rp, csrc, dis, gamma, k);
  }
}

// Round 9
// 551.065 us; speedup vs baseline: 1.1033x; 1.1033x over previous
//
#include <hip/hip_runtime.h>
#include <hip/hip_bf16.h>

#define NN    100000
#define NE    1600000
#define INCH  512
#define HIDCH 256
#define OUTCH 32
#define KHOPS 10
#define NEPAD (NE + 3 * NN)

typedef __attribute__((ext_vector_type(8))) short short8;
typedef __attribute__((ext_vector_type(4))) float f32x4;

#define GLOAD_LDS16(gsrc, ldst) \
  __builtin_amdgcn_global_load_lds((const __attribute__((address_space(1))) void*)(gsrc), \
                                   (__attribute__((address_space(3))) void*)(ldst), 16, 0, 0)

// ---------------- workspace layout ----------------
constexpr size_t ws_align(size_t x) { return (x + 255) & ~(size_t)255; }
constexpr size_t USZ = ws_align((size_t)(NN + 1) * 32 * 2);   // U table bf16 [NN+1][32]
constexpr size_t OFF_H1   = 0;                                           // [NN][256] bf16
constexpr size_t OFF_U0   = OFF_H1   + ws_align((size_t)NN*HIDCH*2);     // parity 0
constexpr size_t OFF_U1   = OFF_U0   + USZ;                              // parity 1
constexpr size_t OFF_W1TH = OFF_U1   + USZ;                              // [256][512] bf16
constexpr size_t OFF_W1TL = OFF_W1TH + ws_align((size_t)HIDCH*INCH*2);
constexpr size_t OFF_W2TH = OFF_W1TL + ws_align((size_t)HIDCH*INCH*2);   // [32][256] bf16
constexpr size_t OFF_W2TL = OFF_W2TH + ws_align((size_t)OUTCH*HIDCH*2);
constexpr size_t OFF_DEG  = OFF_W2TL + ws_align((size_t)OUTCH*HIDCH*2);  // [NN] int
constexpr size_t OFF_DIS  = OFF_DEG  + ws_align((size_t)NN*4);           // [NN] f32
constexpr size_t OFF_RP   = OFF_DIS  + ws_align((size_t)NN*4);           // [NN+1] int (deg rounded to 4)
constexpr size_t OFF_CUR  = OFF_RP   + ws_align((size_t)(NN+1)*4);       // [NN] int
constexpr size_t OFF_CSR  = OFF_CUR  + ws_align((size_t)NN*4);           // [NEPAD] int src
constexpr size_t OFF_PART = OFF_CSR  + ws_align((size_t)NEPAD*4);        // [128] int
constexpr size_t OFF_OFFS = OFF_PART + ws_align(512);                    // [128] int

// ---------------- bf16 helpers ----------------
__device__ __forceinline__ unsigned short bf16_rne(float f) {
  unsigned int u = __float_as_uint(f);
  u += 0x7fffu + ((u >> 16) & 1u);
  return (unsigned short)(u >> 16);
}
__device__ __forceinline__ float bf16_to_f32(unsigned short h) {
  return __uint_as_float(((unsigned int)h) << 16);
}
__device__ __forceinline__ float bflo(unsigned int w) {
  return __uint_as_float(w << 16);
}
__device__ __forceinline__ float bfhi(unsigned int w) {
  return __uint_as_float(w & 0xffff0000u);
}

// ---------------- degree ----------------
__global__ __launch_bounds__(256) void k_count_deg(const int* __restrict__ col,
                                                   int* __restrict__ deg) {
  int e = blockIdx.x * 256 + threadIdx.x;
  if (e < NE) atomicAdd(&deg[col[e]], 1);
}

// dis + zero the U pad rows (row NN of each parity table: 16 uints each)
__global__ __launch_bounds__(256) void k_dis(const int* __restrict__ deg,
                                             float* __restrict__ dis,
                                             unsigned short* u0, unsigned short* u1) {
  int v = blockIdx.x * 256 + threadIdx.x;
  if (v < NN) {
    int d = deg[v];
    dis[v] = d > 0 ? rsqrtf((float)d) : 0.0f;
  }
  if (blockIdx.x == 0) {
    int t = threadIdx.x;
    if (t < 16)      ((unsigned int*)u0)[(size_t)NN * 16 + t] = 0;
    else if (t < 32) ((unsigned int*)u1)[(size_t)NN * 16 + (t - 16)] = 0;
  }
}

// ---------------- exclusive scan over deg rounded-up-to-4 ----------------
__global__ __launch_bounds__(256) void k_scan1(const int* __restrict__ deg,
                                               int* __restrict__ rp,
                                               int* __restrict__ part) {
  __shared__ int s[256];
  int b = blockIdx.x, t = threadIdx.x;
  int base = b * 1024 + t * 4;
  int v0 = (base + 0 < NN) ? ((deg[base + 0] + 3) & ~3) : 0;
  int v1 = (base + 1 < NN) ? ((deg[base + 1] + 3) & ~3) : 0;
  int v2 = (base + 2 < NN) ? ((deg[base + 2] + 3) & ~3) : 0;
  int v3 = (base + 3 < NN) ? ((deg[base + 3] + 3) & ~3) : 0;
  int tot = v0 + v1 + v2 + v3;
  s[t] = tot;
  __syncthreads();
  for (int d = 1; d < 256; d <<= 1) {
    int x = (t >= d) ? s[t - d] : 0;
    __syncthreads();
    s[t] += x;
    __syncthreads();
  }
  int excl = s[t] - tot;
  if (t == 255) part[b] = s[255];
  if (base + 0 < NN) rp[base + 0] = excl;
  if (base + 1 < NN) rp[base + 1] = excl + v0;
  if (base + 2 < NN) rp[base + 2] = excl + v0 + v1;
  if (base + 3 < NN) rp[base + 3] = excl + v0 + v1 + v2;
}

__global__ __launch_bounds__(128) void k_scan2(const int* __restrict__ part,
                                               int* __restrict__ offs) {
  __shared__ int s[128];
  int t = threadIdx.x;
  int v = (t < 98) ? part[t] : 0;
  s[t] = v;
  __syncthreads();
  for (int d = 1; d < 128; d <<= 1) {
    int x = (t >= d) ? s[t - d] : 0;
    __syncthreads();
    s[t] += x;
    __syncthreads();
  }
  if (t < 98) offs[t] = s[t] - v;
}

__global__ __launch_bounds__(256) void k_scan3(int* __restrict__ rp,
                                               const int* __restrict__ offs,
                                               const int* __restrict__ part,
                                               int* __restrict__ cur) {
  int b = blockIdx.x, t = threadIdx.x;
  int o = offs[b];
  int base = b * 1024 + t * 4;
#pragma unroll
  for (int j = 0; j < 4; ++j) {
    int i = base + j;
    if (i < NN) {
      int r = rp[i] + o;
      rp[i] = r;
      cur[i] = r;
    }
  }
  if (b == 0 && t == 0) rp[NN] = offs[97] + part[97];
}

// fill CSR src-only
__global__ __launch_bounds__(256) void k_fill(const int* __restrict__ ei,
                                              int* __restrict__ cur,
                                              int* __restrict__ csrc) {
  int e = blockIdx.x * 256 + threadIdx.x;
  if (e < NE) {
    int c = ei[NE + e];
    int p = atomicAdd(&cur[c], 1);
    csrc[p] = ei[e];
  }
}

// pad each node's slots up to rounded length with dummy src = NN (zero row)
__global__ __launch_bounds__(256) void k_pad(const int* __restrict__ cur,
                                             const int* __restrict__ rp,
                                             int* __restrict__ csrc) {
  int v = blockIdx.x * 256 + threadIdx.x;
  if (v < NN) {
    int p = cur[v], e = rp[v + 1];
    for (; p < e; ++p) csrc[p] = NN;
  }
}

// ---------------- split-transpose: dst[n][k] = split(src[k][n]) ----------------
__global__ __launch_bounds__(256) void k_splitT(const float* __restrict__ src,
                                                unsigned short* __restrict__ dh,
                                                unsigned short* __restrict__ dl,
                                                int K, int N) {
  int idx = blockIdx.x * 256 + threadIdx.x;
  if (idx >= K * N) return;
  int n = idx / K, k = idx - n * K;
  float v = src[(size_t)k * N + n];
  unsigned short h = bf16_rne(v);
  dh[idx] = h;
  dl[idx] = bf16_rne(v - bf16_to_f32(h));
}

// ---------------- GEMM1 (r4 pipeline, SINGLE product Ah*Bh): -----------------------
// H1bf = bf16(relu(X @ W1 + b1)); tile 128x256x32, 8 waves, dbuf LDS 48KB.
// W1 quantized to bf16 (error ~1e-3 into h1, ~7e-4 into out; threshold 8.9e-3).
__global__ __launch_bounds__(512, 2) void k_gemm1(const float* __restrict__ X,
                                                  const unsigned short* __restrict__ W1Th,
                                                  const float* __restrict__ bias1,
                                                  unsigned short* __restrict__ H1bf) {
  __shared__ __align__(16) unsigned short Ah[2][4096];   // 16 KB
  __shared__ __align__(16) unsigned short Bh[2][8192];   // 32 KB
  const int t = threadIdx.x;
  const int m0 = blockIdx.x * 128;
  const int w = t >> 6, lane = t & 63;
  const int wm = w >> 2, wn = w & 3;

  // A staging: thread t -> row t>>2 (0..127), k-chunk t&3 (8 floats)
  const int arow = t >> 2;
  const int achk = t & 3;
  int axrow = m0 + arow; if (axrow >= NN) axrow = NN - 1;
  const float* aptr = X + (size_t)axrow * INCH + achk * 8;
  int aidx = (arow >> 4) * 512 + ((arow & 15) + achk * 16) * 8;
  aidx ^= ((aidx >> 7) & 3) << 4;                      // XOR-swizzle (r3/r4: 0 conflicts)
  const int aroff = (lane * 8) ^ (((lane >> 4) & 3) << 4);

  // B global sources for global_load_lds: wave w covers n-groups {w, w+8}
  const int bn0 = (w * 16) + (lane & 15);
  const int bko = (lane >> 4) * 8;
  const unsigned short* bs0 = W1Th + (size_t)bn0 * INCH + bko;
  const unsigned short* bs1 = W1Th + (size_t)(bn0 + 128) * INCH + bko;

  f32x4 acc[4][4] = {};
  float4 av0, av1;

  // ---- prologue: stage tile 0 into buffer 0 ----
  av0 = *(const float4*)(aptr);
  av1 = *(const float4*)(aptr + 4);
  GLOAD_LDS16(bs0, &Bh[0][w * 512]);
  GLOAD_LDS16(bs1, &Bh[0][(w + 8) * 512]);
  {
    float af[8] = {av0.x, av0.y, av0.z, av0.w, av1.x, av1.y, av1.z, av1.w};
    short8 ah;
#pragma unroll
    for (int i = 0; i < 8; ++i) {
      unsigned int u = __float_as_uint(af[i]);
      ah[i] = (short)((u + 0x7fffu + ((u >> 16) & 1u)) >> 16);
    }
    *(short8*)&Ah[0][aidx] = ah;
  }
  __syncthreads();

#pragma unroll
  for (int it = 0; it < 16; ++it) {
    const int cur = it & 1, nxt = cur ^ 1;
    const int k0 = it * 32;
    // prefetch tile it+1 (issue BEFORE this tile's MFMAs; drained at end barrier)
    if (it < 15) {
      av0 = *(const float4*)(aptr + k0 + 32);
      av1 = *(const float4*)(aptr + k0 + 36);
      GLOAD_LDS16(bs0 + k0 + 32, &Bh[nxt][w * 512]);
      GLOAD_LDS16(bs1 + k0 + 32, &Bh[nxt][(w + 8) * 512]);
    }
    // compute on buffer cur
    short8 afrag[4];
#pragma unroll
    for (int mf = 0; mf < 4; ++mf)
      afrag[mf] = *(const short8*)&Ah[cur][(wm * 4 + mf) * 512 + aroff];
#pragma unroll
    for (int nf = 0; nf < 4; ++nf) {
      short8 bfh = *(const short8*)&Bh[cur][(wn * 4 + nf) * 512 + lane * 8];
#pragma unroll
      for (int mf = 0; mf < 4; ++mf) {
        acc[mf][nf] = __builtin_amdgcn_mfma_f32_16x16x32_bf16(afrag[mf], bfh, acc[mf][nf], 0, 0, 0);
      }
    }
    // A split + write for next tile (after MFMAs; only waits on its own 2 loads)
    if (it < 15) {
      float af[8] = {av0.x, av0.y, av0.z, av0.w, av1.x, av1.y, av1.z, av1.w};
      short8 ah;
#pragma unroll
      for (int i = 0; i < 8; ++i) {
        unsigned int u = __float_as_uint(af[i]);
        ah[i] = (short)((u + 0x7fffu + ((u >> 16) & 1u)) >> 16);
      }
      *(short8*)&Ah[nxt][aidx] = ah;
    }
    __syncthreads();
  }

  // epilogue: +bias, relu, cvt bf16, store
  const int colbase = wn * 64 + (lane & 15);
  const int rowbase = m0 + wm * 64 + ((lane >> 4) << 2);
#pragma unroll
  for (int nf = 0; nf < 4; ++nf) {
    int col = colbase + nf * 16;
    float b = bias1[col];
#pragma unroll
    for (int mf = 0; mf < 4; ++mf) {
#pragma unroll
      for (int r = 0; r < 4; ++r) {
        int row = rowbase + mf * 16 + r;
        if (row < NN) {
          float h = fmaxf(acc[mf][nf][r] + b, 0.f);
          H1bf[(size_t)row * HIDCH + col] = bf16_rne(h);
        }
      }
    }
  }
}

// ---------------- GEMM2: h = H1bf @ W2 + b2; u0 = bf16(dis*h); out = g0*h ---------
__global__ __launch_bounds__(256) void k_gemm2(const unsigned short* __restrict__ H1bf,
                                               const unsigned short* __restrict__ W2Th,
                                               const unsigned short* __restrict__ W2Tl,
                                               const float* __restrict__ bias2,
                                               const float* __restrict__ gamma,
                                               const float* __restrict__ dis,
                                               unsigned short* __restrict__ u0,
                                               float* __restrict__ out) {
  __shared__ __align__(16) unsigned short A2[8192];
  __shared__ __align__(16) unsigned short B2h[2048], B2l[2048];
  const int t = threadIdx.x;
  const int m0 = blockIdx.x * 128;

  const int arow = t >> 1;
  int axrow = m0 + arow; if (axrow >= NN) axrow = NN - 1;
  const int akb = (t & 1) * 32;
  const unsigned short* ap = H1bf + (size_t)axrow * HIDCH + akb;
  const int abase = ((arow >> 4) * 2 + (akb >> 5)) * 512 + (arow & 15) * 8;

  const int bnr = t >> 3, bkq = (t & 7) * 8;
  const int bslot = ((bnr >> 4) * 2 + (bkq >> 5)) * 512 +
                    ((bnr & 15) + (((bkq & 31) >> 3) << 4)) * 8;
  const unsigned short* bhp = W2Th + (size_t)bnr * HIDCH + bkq;
  const unsigned short* blp = W2Tl + (size_t)bnr * HIDCH + bkq;

  const int w = t >> 6, lane = t & 63;

  f32x4 acc[2][2] = {};

  for (int k0 = 0; k0 < HIDCH; k0 += 64) {
    uint4 a0 = *(const uint4*)(ap + k0);
    uint4 a1 = *(const uint4*)(ap + k0 + 8);
    uint4 a2 = *(const uint4*)(ap + k0 + 16);
    uint4 a3 = *(const uint4*)(ap + k0 + 24);
    uint4 bh = *(const uint4*)(bhp + k0);
    uint4 bl = *(const uint4*)(blp + k0);

    __syncthreads();

    *(uint4*)&A2[abase + 0 * 128] = a0;
    *(uint4*)&A2[abase + 1 * 128] = a1;
    *(uint4*)&A2[abase + 2 * 128] = a2;
    *(uint4*)&A2[abase + 3 * 128] = a3;
    *(uint4*)&B2h[bslot] = bh;
    *(uint4*)&B2l[bslot] = bl;

    __syncthreads();

    const short8* AV  = (const short8*)A2;
    const short8* BHV = (const short8*)B2h;
    const short8* BLV = (const short8*)B2l;
#pragma unroll
    for (int k32 = 0; k32 < 2; ++k32) {
      short8 bfh[2], bfl[2];
#pragma unroll
      for (int nf = 0; nf < 2; ++nf) {
        bfh[nf] = BHV[(nf * 2 + k32) * 64 + lane];
        bfl[nf] = BLV[(nf * 2 + k32) * 64 + lane];
      }
#pragma unroll
      for (int mf = 0; mf < 2; ++mf) {
        short8 a = AV[((w * 2 + mf) * 2 + k32) * 64 + lane];
#pragma unroll
        for (int nf = 0; nf < 2; ++nf) {
          acc[mf][nf] = __builtin_amdgcn_mfma_f32_16x16x32_bf16(a, bfh[nf], acc[mf][nf], 0, 0, 0);
          acc[mf][nf] = __builtin_amdgcn_mfma_f32_16x16x32_bf16(a, bfl[nf], acc[mf][nf], 0, 0, 0);
        }
      }
    }
  }

  const float g0 = gamma[0];
  const int colb = lane & 15;
  const int rowb = m0 + w * 32 + ((lane >> 4) << 2);
  const float b2c0 = bias2[colb], b2c1 = bias2[16 + colb];
#pragma unroll
  for (int mf = 0; mf < 2; ++mf) {
#pragma unroll
    for (int r = 0; r < 4; ++r) {
      int row = rowb + mf * 16 + r;
      if (row < NN) {
        float dv = dis[row];
        float h0 = acc[mf][0][r] + b2c0;
        float h1 = acc[mf][1][r] + b2c1;
        size_t o = (size_t)row * 32 + colb;
        u0[o] = bf16_rne(dv * h0);
        u0[o + 16] = bf16_rne(dv * h1);
        out[o] = g0 * h0;
        out[o + 16] = g0 * h1;
      }
    }
  }
}

// ---------------- hop: full 32-ch rows, 16 lanes/node -----------------------------
// u_k[v] = dis^2[v] * sum_src u_{k-1}[src];  out[v] += gamma_k * dis[v] * sum.
// One edge visit per edge (64B source row = 1 segment). Meta int4 uniform per group.
__global__ __launch_bounds__(256) void k_hop(const unsigned short* __restrict__ Uin,
                                             unsigned short* __restrict__ Uout,
                                             float* __restrict__ out,
                                             const int* __restrict__ rp,
                                             const int* __restrict__ csrc,
                                             const float* __restrict__ dis,
                                             const float* __restrict__ gamma,
                                             int k) {
  const int t = threadIdx.x;
  const int g = t >> 4;                    // node slot 0..15
  const int li = t & 15;                   // lane in group (2 channels)
  const int v = blockIdx.x * 16 + g;
  const int s = rp[v], e = rp[v + 1];      // multiples of 4 (src=NN pads -> zero row)
  const unsigned int* Uin32 = (const unsigned int*)Uin;

  float ax0 = 0.f, ay0 = 0.f, ax1 = 0.f, ay1 = 0.f;
  float ax2 = 0.f, ay2 = 0.f, ax3 = 0.f, ay3 = 0.f;
  int j = s;
  for (; j + 8 <= e; j += 8) {
    int4 sa = *(const int4*)&csrc[j];      // uniform within group -> broadcast
    int4 sb = *(const int4*)&csrc[j + 4];
    unsigned int w0 = Uin32[(size_t)sa.x * 16 + li];
    unsigned int w1 = Uin32[(size_t)sa.y * 16 + li];
    unsigned int w2 = Uin32[(size_t)sa.z * 16 + li];
    unsigned int w3 = Uin32[(size_t)sa.w * 16 + li];
    unsigned int w4 = Uin32[(size_t)sb.x * 16 + li];
    unsigned int w5 = Uin32[(size_t)sb.y * 16 + li];
    unsigned int w6 = Uin32[(size_t)sb.z * 16 + li];
    unsigned int w7 = Uin32[(size_t)sb.w * 16 + li];
    ax0 += bflo(w0); ay0 += bfhi(w0);
    ax1 += bflo(w1); ay1 += bfhi(w1);
    ax2 += bflo(w2); ay2 += bfhi(w2);
    ax3 += bflo(w3); ay3 += bfhi(w3);
    ax0 += bflo(w4); ay0 += bfhi(w4);
    ax1 += bflo(w5); ay1 += bfhi(w5);
    ax2 += bflo(w6); ay2 += bfhi(w6);
    ax3 += bflo(w7); ay3 += bfhi(w7);
  }
  if (j < e) {
    int4 sa = *(const int4*)&csrc[j];
    unsigned int w0 = Uin32[(size_t)sa.x * 16 + li];
    unsigned int w1 = Uin32[(size_t)sa.y * 16 + li];
    unsigned int w2 = Uin32[(size_t)sa.z * 16 + li];
    unsigned int w3 = Uin32[(size_t)sa.w * 16 + li];
    ax0 += bflo(w0); ay0 += bfhi(w0);
    ax1 += bflo(w1); ay1 += bfhi(w1);
    ax2 += bflo(w2); ay2 += bfhi(w2);
    ax3 += bflo(w3); ay3 += bfhi(w3);
  }
  const float Sx = (ax0 + ax1) + (ax2 + ax3);
  const float Sy = (ay0 + ay1) + (ay2 + ay3);
  const float dv = dis[v];
  const float gd = gamma[k] * dv;
  const float d2 = dv * dv;
  unsigned int packed = (unsigned int)bf16_rne(d2 * Sx) |
                        ((unsigned int)bf16_rne(d2 * Sy) << 16);
  ((unsigned int*)Uout)[(size_t)v * 16 + li] = packed;
  const size_t o = (size_t)v * 32 + li * 2;
  float2 po = *(const float2*)&out[o];
  po.x = fmaf(gd, Sx, po.x);
  po.y = fmaf(gd, Sy, po.y);
  *(float2*)&out[o] = po;
}

extern "C" void kernel_launch(void* const* d_in, const int* in_sizes, int n_in,
                              void* d_out, int out_size, void* d_ws, size_t ws_size,
                              hipStream_t stream) {
  const float* x     = (const float*)d_in[0];
  const int*   ei    = (const int*)d_in[1];
  const float* W1    = (const float*)d_in[2];
  const float* b1    = (const float*)d_in[3];
  const float* W2    = (const float*)d_in[4];
  const float* b2    = (const float*)d_in[5];
  const float* gamma = (const float*)d_in[6];
  float* out = (float*)d_out;

  char* ws = (char*)d_ws;
  unsigned short* h1bf = (unsigned short*)(ws + OFF_H1);
  unsigned short* U[2] = {(unsigned short*)(ws + OFF_U0),
                          (unsigned short*)(ws + OFF_U1)};
  unsigned short* w1th = (unsigned short*)(ws + OFF_W1TH);
  unsigned short* w1tl = (unsigned short*)(ws + OFF_W1TL);
  unsigned short* w2th = (unsigned short*)(ws + OFF_W2TH);
  unsigned short* w2tl = (unsigned short*)(ws + OFF_W2TL);
  int*   deg  = (int*)(ws + OFF_DEG);
  float* dis  = (float*)(ws + OFF_DIS);
  int*   rp   = (int*)(ws + OFF_RP);
  int*   cur  = (int*)(ws + OFF_CUR);
  int*   csrc = (int*)(ws + OFF_CSR);
  int*   part = (int*)(ws + OFF_PART);
  int*   offs = (int*)(ws + OFF_OFFS);

  hipMemsetAsync(deg, 0, NN * sizeof(int), stream);

  // weight prep (tiny)
  k_splitT<<<(INCH * HIDCH + 255) / 256, 256, 0, stream>>>(W1, w1th, w1tl, INCH, HIDCH);
  k_splitT<<<(HIDCH * OUTCH + 255) / 256, 256, 0, stream>>>(W2, w2th, w2tl, HIDCH, OUTCH);

  // graph prep
  k_count_deg<<<(NE + 255) / 256, 256, 0, stream>>>(ei + NE, deg);
  k_dis<<<(NN + 255) / 256, 256, 0, stream>>>(deg, dis, U[0], U[1]);
  k_scan1<<<98, 256, 0, stream>>>(deg, rp, part);
  k_scan2<<<1, 128, 0, stream>>>(part, offs);
  k_scan3<<<98, 256, 0, stream>>>(rp, offs, part, cur);
  k_fill<<<(NE + 255) / 256, 256, 0, stream>>>(ei, cur, csrc);
  k_pad<<<(NN + 255) / 256, 256, 0, stream>>>(cur, rp, csrc);

  // MLP
  k_gemm1<<<(NN + 127) / 128, 512, 0, stream>>>(x, w1th, b1, h1bf);
  k_gemm2<<<(NN + 127) / 128, 256, 0, stream>>>(h1bf, w2th, w2tl, b2, gamma, dis,
                                                U[0], out);

  // propagation: 10 hops, full 32-ch rows, gamma accumulated straight into out
  for (int k = 1; k <= KHOPS; ++k) {
    k_hop<<<NN / 16, 256, 0, stream>>>(U[(k - 1) & 1], U[k & 1], out,
                                       rp, csrc, dis, gamma, k);
  }
}

// Round 10
// 527.697 us; speedup vs baseline: 1.1522x; 1.0443x over previous
//
#include <hip/hip_runtime.h>
#include <hip/hip_bf16.h>

#define NN    100000
#define NE    1600000
#define INCH  512
#define HIDCH 256
#define OUTCH 32
#define KHOPS 10
#define NEPAD (NE + 3 * NN)
#define NBKT  8
#define BDIV  12500            // NN / NBKT
#define BCAP  204800           // per-bucket capacity (mean 200K + 11 sigma)
#define EPB_A 8192             // edges per block, bucket phase
#define EPB_B 2048             // edges per block, fill phase

typedef __attribute__((ext_vector_type(8))) short short8;
typedef __attribute__((ext_vector_type(4))) float f32x4;

#define GLOAD_LDS16(gsrc, ldst) \
  __builtin_amdgcn_global_load_lds((const __attribute__((address_space(1))) void*)(gsrc), \
                                   (__attribute__((address_space(3))) void*)(ldst), 16, 0, 0)

// ---------------- workspace layout ----------------
constexpr size_t ws_align(size_t x) { return (x + 255) & ~(size_t)255; }
constexpr size_t USZ = ws_align((size_t)(NN + 1) * 32 * 2);   // U table bf16 [NN+1][32]
constexpr size_t OFF_H1   = 0;                                           // [NN][256] bf16
constexpr size_t OFF_U0   = OFF_H1   + ws_align((size_t)NN*HIDCH*2);     // parity 0
constexpr size_t OFF_U1   = OFF_U0   + USZ;                              // parity 1
constexpr size_t OFF_W1TH = OFF_U1   + USZ;                              // [256][512] bf16
constexpr size_t OFF_W1TL = OFF_W1TH + ws_align((size_t)HIDCH*INCH*2);
constexpr size_t OFF_W2TH = OFF_W1TL + ws_align((size_t)HIDCH*INCH*2);   // [32][256] bf16
constexpr size_t OFF_W2TL = OFF_W2TH + ws_align((size_t)OUTCH*HIDCH*2);
constexpr size_t OFF_DEG  = OFF_W2TL + ws_align((size_t)OUTCH*HIDCH*2);  // [NN] int
constexpr size_t OFF_DIS  = OFF_DEG  + ws_align((size_t)NN*4);           // [NN] f32
constexpr size_t OFF_RP   = OFF_DIS  + ws_align((size_t)NN*4);           // [NN+1] int (deg rounded to 4)
constexpr size_t OFF_CUR  = OFF_RP   + ws_align((size_t)(NN+1)*4);       // [NN] int
constexpr size_t OFF_CSR  = OFF_CUR  + ws_align((size_t)NN*4);           // [NEPAD] int src
constexpr size_t OFF_PART = OFF_CSR  + ws_align((size_t)NEPAD*4);        // [128] int
constexpr size_t OFF_OFFS = OFF_PART + ws_align(512);                    // [128] int
constexpr size_t OFF_BCNT = OFF_OFFS + ws_align(512);                    // [8] int
constexpr size_t OFF_EPK8 = OFF_BCNT + ws_align(32);                     // [8][BCAP] int2

// ---------------- bf16 helpers ----------------
__device__ __forceinline__ unsigned short bf16_rne(float f) {
  unsigned int u = __float_as_uint(f);
  u += 0x7fffu + ((u >> 16) & 1u);
  return (unsigned short)(u >> 16);
}
__device__ __forceinline__ float bf16_to_f32(unsigned short h) {
  return __uint_as_float(((unsigned int)h) << 16);
}
__device__ __forceinline__ float bflo(unsigned int w) {
  return __uint_as_float(w << 16);
}
__device__ __forceinline__ float bfhi(unsigned int w) {
  return __uint_as_float(w & 0xffff0000u);
}

// ---------------- phase A: bucket edges by destination range + count deg ----------
// Per-block LDS histogram -> one global reservation per bucket -> contiguous runs
// (full-line dirtiness within one block/XCD; kills 64B-per-4B write amplification).
__global__ __launch_bounds__(256) void k_bucket(const int* __restrict__ ei,
                                                int* __restrict__ deg,
                                                int* __restrict__ bcnt,
                                                int2* __restrict__ epk8) {
  __shared__ int hist[NBKT], rbase[NBKT], lcur[NBKT];
  const int t = threadIdx.x;
  const int e0 = blockIdx.x * EPB_A;
  if (t < NBKT) hist[t] = 0;
  __syncthreads();
  for (int i = t; i < EPB_A; i += 256) {
    int e = e0 + i;
    if (e < NE) {
      int c = ei[NE + e];
      atomicAdd(&deg[c], 1);
      atomicAdd(&hist[c / BDIV], 1);
    }
  }
  __syncthreads();
  if (t < NBKT) {
    rbase[t] = atomicAdd(&bcnt[t], hist[t]);
    lcur[t] = 0;
  }
  __syncthreads();
  for (int i = t; i < EPB_A; i += 256) {
    int e = e0 + i;
    if (e < NE) {
      int r = ei[e], c = ei[NE + e];
      int b = c / BDIV;
      int slot = atomicAdd(&lcur[b], 1);
      epk8[(size_t)b * BCAP + rbase[b] + slot] = make_int2(r, c);
    }
  }
}

// ---------------- phase B: fill CSR, XCD-matched (bid%8 == bucket == XCD) ---------
__global__ __launch_bounds__(256) void k_fill2(const int2* __restrict__ epk8,
                                               const int* __restrict__ bcnt,
                                               int* __restrict__ cur,
                                               int* __restrict__ csrc) {
  const int bucket = blockIdx.x & 7;
  const int chunk = blockIdx.x >> 3;
  const int cnt = bcnt[bucket];
  const int lo = chunk * EPB_B;
  int n = cnt - lo;
  if (n > EPB_B) n = EPB_B;
  const int2* src = epk8 + (size_t)bucket * BCAP + lo;
  for (int i = threadIdx.x; i < n; i += 256) {
    int2 rc = src[i];
    int p = atomicAdd(&cur[rc.y], 1);
    csrc[p] = rc.x;
  }
}

// dis + zero the U pad rows (row NN of each parity table: 16 uints each)
__global__ __launch_bounds__(256) void k_dis(const int* __restrict__ deg,
                                             float* __restrict__ dis,
                                             unsigned short* u0, unsigned short* u1) {
  int v = blockIdx.x * 256 + threadIdx.x;
  if (v < NN) {
    int d = deg[v];
    dis[v] = d > 0 ? rsqrtf((float)d) : 0.0f;
  }
  if (blockIdx.x == 0) {
    int t = threadIdx.x;
    if (t < 16)      ((unsigned int*)u0)[(size_t)NN * 16 + t] = 0;
    else if (t < 32) ((unsigned int*)u1)[(size_t)NN * 16 + (t - 16)] = 0;
  }
}

// ---------------- exclusive scan over deg rounded-up-to-4 ----------------
__global__ __launch_bounds__(256) void k_scan1(const int* __restrict__ deg,
                                               int* __restrict__ rp,
                                               int* __restrict__ part) {
  __shared__ int s[256];
  int b = blockIdx.x, t = threadIdx.x;
  int base = b * 1024 + t * 4;
  int v0 = (base + 0 < NN) ? ((deg[base + 0] + 3) & ~3) : 0;
  int v1 = (base + 1 < NN) ? ((deg[base + 1] + 3) & ~3) : 0;
  int v2 = (base + 2 < NN) ? ((deg[base + 2] + 3) & ~3) : 0;
  int v3 = (base + 3 < NN) ? ((deg[base + 3] + 3) & ~3) : 0;
  int tot = v0 + v1 + v2 + v3;
  s[t] = tot;
  __syncthreads();
  for (int d = 1; d < 256; d <<= 1) {
    int x = (t >= d) ? s[t - d] : 0;
    __syncthreads();
    s[t] += x;
    __syncthreads();
  }
  int excl = s[t] - tot;
  if (t == 255) part[b] = s[255];
  if (base + 0 < NN) rp[base + 0] = excl;
  if (base + 1 < NN) rp[base + 1] = excl + v0;
  if (base + 2 < NN) rp[base + 2] = excl + v0 + v1;
  if (base + 3 < NN) rp[base + 3] = excl + v0 + v1 + v2;
}

__global__ __launch_bounds__(128) void k_scan2(const int* __restrict__ part,
                                               int* __restrict__ offs) {
  __shared__ int s[128];
  int t = threadIdx.x;
  int v = (t < 98) ? part[t] : 0;
  s[t] = v;
  __syncthreads();
  for (int d = 1; d < 128; d <<= 1) {
    int x = (t >= d) ? s[t - d] : 0;
    __syncthreads();
    s[t] += x;
    __syncthreads();
  }
  if (t < 98) offs[t] = s[t] - v;
}

__global__ __launch_bounds__(256) void k_scan3(int* __restrict__ rp,
                                               const int* __restrict__ offs,
                                               const int* __restrict__ part,
                                               int* __restrict__ cur) {
  int b = blockIdx.x, t = threadIdx.x;
  int o = offs[b];
  int base = b * 1024 + t * 4;
#pragma unroll
  for (int j = 0; j < 4; ++j) {
    int i = base + j;
    if (i < NN) {
      int r = rp[i] + o;
      rp[i] = r;
      cur[i] = r;
    }
  }
  if (b == 0 && t == 0) rp[NN] = offs[97] + part[97];
}

// pad each node's slots up to rounded length with dummy src = NN (zero row)
__global__ __launch_bounds__(256) void k_pad(const int* __restrict__ cur,
                                             const int* __restrict__ rp,
                                             int* __restrict__ csrc) {
  int v = blockIdx.x * 256 + threadIdx.x;
  if (v < NN) {
    int p = cur[v], e = rp[v + 1];
    for (; p < e; ++p) csrc[p] = NN;
  }
}

// ---------------- split-transpose: dst[n][k] = split(src[k][n]) ----------------
__global__ __launch_bounds__(256) void k_splitT(const float* __restrict__ src,
                                                unsigned short* __restrict__ dh,
                                                unsigned short* __restrict__ dl,
                                                int K, int N) {
  int idx = blockIdx.x * 256 + threadIdx.x;
  if (idx >= K * N) return;
  int n = idx / K, k = idx - n * K;
  float v = src[(size_t)k * N + n];
  unsigned short h = bf16_rne(v);
  dh[idx] = h;
  dl[idx] = bf16_rne(v - bf16_to_f32(h));
}

// ---------------- GEMM1 (r4 pipeline, single product Ah*Bh) -----------------------
// H1bf = bf16(relu(X @ W1 + b1)); tile 128x256x32, 8 waves, dbuf LDS 48KB.
__global__ __launch_bounds__(512, 2) void k_gemm1(const float* __restrict__ X,
                                                  const unsigned short* __restrict__ W1Th,
                                                  const float* __restrict__ bias1,
                                                  unsigned short* __restrict__ H1bf) {
  __shared__ __align__(16) unsigned short Ah[2][4096];   // 16 KB
  __shared__ __align__(16) unsigned short Bh[2][8192];   // 32 KB
  const int t = threadIdx.x;
  const int m0 = blockIdx.x * 128;
  const int w = t >> 6, lane = t & 63;
  const int wm = w >> 2, wn = w & 3;

  const int arow = t >> 2;
  const int achk = t & 3;
  int axrow = m0 + arow; if (axrow >= NN) axrow = NN - 1;
  const float* aptr = X + (size_t)axrow * INCH + achk * 8;
  int aidx = (arow >> 4) * 512 + ((arow & 15) + achk * 16) * 8;
  aidx ^= ((aidx >> 7) & 3) << 4;                      // XOR-swizzle (0 conflicts)
  const int aroff = (lane * 8) ^ (((lane >> 4) & 3) << 4);

  const int bn0 = (w * 16) + (lane & 15);
  const int bko = (lane >> 4) * 8;
  const unsigned short* bs0 = W1Th + (size_t)bn0 * INCH + bko;
  const unsigned short* bs1 = W1Th + (size_t)(bn0 + 128) * INCH + bko;

  f32x4 acc[4][4] = {};
  float4 av0, av1;

  av0 = *(const float4*)(aptr);
  av1 = *(const float4*)(aptr + 4);
  GLOAD_LDS16(bs0, &Bh[0][w * 512]);
  GLOAD_LDS16(bs1, &Bh[0][(w + 8) * 512]);
  {
    float af[8] = {av0.x, av0.y, av0.z, av0.w, av1.x, av1.y, av1.z, av1.w};
    short8 ah;
#pragma unroll
    for (int i = 0; i < 8; ++i) {
      unsigned int u = __float_as_uint(af[i]);
      ah[i] = (short)((u + 0x7fffu + ((u >> 16) & 1u)) >> 16);
    }
    *(short8*)&Ah[0][aidx] = ah;
  }
  __syncthreads();

#pragma unroll
  for (int it = 0; it < 16; ++it) {
    const int cur = it & 1, nxt = cur ^ 1;
    const int k0 = it * 32;
    if (it < 15) {
      av0 = *(const float4*)(aptr + k0 + 32);
      av1 = *(const float4*)(aptr + k0 + 36);
      GLOAD_LDS16(bs0 + k0 + 32, &Bh[nxt][w * 512]);
      GLOAD_LDS16(bs1 + k0 + 32, &Bh[nxt][(w + 8) * 512]);
    }
    short8 afrag[4];
#pragma unroll
    for (int mf = 0; mf < 4; ++mf)
      afrag[mf] = *(const short8*)&Ah[cur][(wm * 4 + mf) * 512 + aroff];
#pragma unroll
    for (int nf = 0; nf < 4; ++nf) {
      short8 bfh = *(const short8*)&Bh[cur][(wn * 4 + nf) * 512 + lane * 8];
#pragma unroll
      for (int mf = 0; mf < 4; ++mf) {
        acc[mf][nf] = __builtin_amdgcn_mfma_f32_16x16x32_bf16(afrag[mf], bfh, acc[mf][nf], 0, 0, 0);
      }
    }
    if (it < 15) {
      float af[8] = {av0.x, av0.y, av0.z, av0.w, av1.x, av1.y, av1.z, av1.w};
      short8 ah;
#pragma unroll
      for (int i = 0; i < 8; ++i) {
        unsigned int u = __float_as_uint(af[i]);
        ah[i] = (short)((u + 0x7fffu + ((u >> 16) & 1u)) >> 16);
      }
      *(short8*)&Ah[nxt][aidx] = ah;
    }
    __syncthreads();
  }

  const int colbase = wn * 64 + (lane & 15);
  const int rowbase = m0 + wm * 64 + ((lane >> 4) << 2);
#pragma unroll
  for (int nf = 0; nf < 4; ++nf) {
    int col = colbase + nf * 16;
    float b = bias1[col];
#pragma unroll
    for (int mf = 0; mf < 4; ++mf) {
#pragma unroll
      for (int r = 0; r < 4; ++r) {
        int row = rowbase + mf * 16 + r;
        if (row < NN) {
          float h = fmaxf(acc[mf][nf][r] + b, 0.f);
          H1bf[(size_t)row * HIDCH + col] = bf16_rne(h);
        }
      }
    }
  }
}

// ---------------- GEMM2: h = H1bf @ W2 + b2; u0 = bf16(dis*h); out = g0*h ---------
__global__ __launch_bounds__(256) void k_gemm2(const unsigned short* __restrict__ H1bf,
                                               const unsigned short* __restrict__ W2Th,
                                               const unsigned short* __restrict__ W2Tl,
                                               const float* __restrict__ bias2,
                                               const float* __restrict__ gamma,
                                               const float* __restrict__ dis,
                                               unsigned short* __restrict__ u0,
                                               float* __restrict__ out) {
  __shared__ __align__(16) unsigned short A2[8192];
  __shared__ __align__(16) unsigned short B2h[2048], B2l[2048];
  const int t = threadIdx.x;
  const int m0 = blockIdx.x * 128;

  const int arow = t >> 1;
  int axrow = m0 + arow; if (axrow >= NN) axrow = NN - 1;
  const int akb = (t & 1) * 32;
  const unsigned short* ap = H1bf + (size_t)axrow * HIDCH + akb;
  const int abase = ((arow >> 4) * 2 + (akb >> 5)) * 512 + (arow & 15) * 8;

  const int bnr = t >> 3, bkq = (t & 7) * 8;
  const int bslot = ((bnr >> 4) * 2 + (bkq >> 5)) * 512 +
                    ((bnr & 15) + (((bkq & 31) >> 3) << 4)) * 8;
  const unsigned short* bhp = W2Th + (size_t)bnr * HIDCH + bkq;
  const unsigned short* blp = W2Tl + (size_t)bnr * HIDCH + bkq;

  const int w = t >> 6, lane = t & 63;

  f32x4 acc[2][2] = {};

  for (int k0 = 0; k0 < HIDCH; k0 += 64) {
    uint4 a0 = *(const uint4*)(ap + k0);
    uint4 a1 = *(const uint4*)(ap + k0 + 8);
    uint4 a2 = *(const uint4*)(ap + k0 + 16);
    uint4 a3 = *(const uint4*)(ap + k0 + 24);
    uint4 bh = *(const uint4*)(bhp + k0);
    uint4 bl = *(const uint4*)(blp + k0);

    __syncthreads();

    *(uint4*)&A2[abase + 0 * 128] = a0;
    *(uint4*)&A2[abase + 1 * 128] = a1;
    *(uint4*)&A2[abase + 2 * 128] = a2;
    *(uint4*)&A2[abase + 3 * 128] = a3;
    *(uint4*)&B2h[bslot] = bh;
    *(uint4*)&B2l[bslot] = bl;

    __syncthreads();

    const short8* AV  = (const short8*)A2;
    const short8* BHV = (const short8*)B2h;
    const short8* BLV = (const short8*)B2l;
#pragma unroll
    for (int k32 = 0; k32 < 2; ++k32) {
      short8 bfh[2], bfl[2];
#pragma unroll
      for (int nf = 0; nf < 2; ++nf) {
        bfh[nf] = BHV[(nf * 2 + k32) * 64 + lane];
        bfl[nf] = BLV[(nf * 2 + k32) * 64 + lane];
      }
#pragma unroll
      for (int mf = 0; mf < 2; ++mf) {
        short8 a = AV[((w * 2 + mf) * 2 + k32) * 64 + lane];
#pragma unroll
        for (int nf = 0; nf < 2; ++nf) {
          acc[mf][nf] = __builtin_amdgcn_mfma_f32_16x16x32_bf16(a, bfh[nf], acc[mf][nf], 0, 0, 0);
          acc[mf][nf] = __builtin_amdgcn_mfma_f32_16x16x32_bf16(a, bfl[nf], acc[mf][nf], 0, 0, 0);
        }
      }
    }
  }

  const float g0 = gamma[0];
  const int colb = lane & 15;
  const int rowb = m0 + w * 32 + ((lane >> 4) << 2);
  const float b2c0 = bias2[colb], b2c1 = bias2[16 + colb];
#pragma unroll
  for (int mf = 0; mf < 2; ++mf) {
#pragma unroll
    for (int r = 0; r < 4; ++r) {
      int row = rowb + mf * 16 + r;
      if (row < NN) {
        float dv = dis[row];
        float h0 = acc[mf][0][r] + b2c0;
        float h1 = acc[mf][1][r] + b2c1;
        size_t o = (size_t)row * 32 + colb;
        u0[o] = bf16_rne(dv * h0);
        u0[o + 16] = bf16_rne(dv * h1);
        out[o] = g0 * h0;
        out[o + 16] = g0 * h1;
      }
    }
  }
}

// ---------------- hop: full 32-ch rows, 16 lanes/node -----------------------------
__global__ __launch_bounds__(256) void k_hop(const unsigned short* __restrict__ Uin,
                                             unsigned short* __restrict__ Uout,
                                             float* __restrict__ out,
                                             const int* __restrict__ rp,
                                             const int* __restrict__ csrc,
                                             const float* __restrict__ dis,
                                             const float* __restrict__ gamma,
                                             int k) {
  const int t = threadIdx.x;
  const int g = t >> 4;                    // node slot 0..15
  const int li = t & 15;                   // lane in group (2 channels)
  const int v = blockIdx.x * 16 + g;
  const int s = rp[v], e = rp[v + 1];      // multiples of 4 (src=NN pads -> zero row)
  const unsigned int* Uin32 = (const unsigned int*)Uin;

  float ax0 = 0.f, ay0 = 0.f, ax1 = 0.f, ay1 = 0.f;
  float ax2 = 0.f, ay2 = 0.f, ax3 = 0.f, ay3 = 0.f;
  int j = s;
  for (; j + 8 <= e; j += 8) {
    int4 sa = *(const int4*)&csrc[j];
    int4 sb = *(const int4*)&csrc[j + 4];
    unsigned int w0 = Uin32[(size_t)sa.x * 16 + li];
    unsigned int w1 = Uin32[(size_t)sa.y * 16 + li];
    unsigned int w2 = Uin32[(size_t)sa.z * 16 + li];
    unsigned int w3 = Uin32[(size_t)sa.w * 16 + li];
    unsigned int w4 = Uin32[(size_t)sb.x * 16 + li];
    unsigned int w5 = Uin32[(size_t)sb.y * 16 + li];
    unsigned int w6 = Uin32[(size_t)sb.z * 16 + li];
    unsigned int w7 = Uin32[(size_t)sb.w * 16 + li];
    ax0 += bflo(w0); ay0 += bfhi(w0);
    ax1 += bflo(w1); ay1 += bfhi(w1);
    ax2 += bflo(w2); ay2 += bfhi(w2);
    ax3 += bflo(w3); ay3 += bfhi(w3);
    ax0 += bflo(w4); ay0 += bfhi(w4);
    ax1 += bflo(w5); ay1 += bfhi(w5);
    ax2 += bflo(w6); ay2 += bfhi(w6);
    ax3 += bflo(w7); ay3 += bfhi(w7);
  }
  if (j < e) {
    int4 sa = *(const int4*)&csrc[j];
    unsigned int w0 = Uin32[(size_t)sa.x * 16 + li];
    unsigned int w1 = Uin32[(size_t)sa.y * 16 + li];
    unsigned int w2 = Uin32[(size_t)sa.z * 16 + li];
    unsigned int w3 = Uin32[(size_t)sa.w * 16 + li];
    ax0 += bflo(w0); ay0 += bfhi(w0);
    ax1 += bflo(w1); ay1 += bfhi(w1);
    ax2 += bflo(w2); ay2 += bfhi(w2);
    ax3 += bflo(w3); ay3 += bfhi(w3);
  }
  const float Sx = (ax0 + ax1) + (ax2 + ax3);
  const float Sy = (ay0 + ay1) + (ay2 + ay3);
  const float dv = dis[v];
  const float gd = gamma[k] * dv;
  const float d2 = dv * dv;
  unsigned int packed = (unsigned int)bf16_rne(d2 * Sx) |
                        ((unsigned int)bf16_rne(d2 * Sy) << 16);
  ((unsigned int*)Uout)[(size_t)v * 16 + li] = packed;
  const size_t o = (size_t)v * 32 + li * 2;
  float2 po = *(const float2*)&out[o];
  po.x = fmaf(gd, Sx, po.x);
  po.y = fmaf(gd, Sy, po.y);
  *(float2*)&out[o] = po;
}

extern "C" void kernel_launch(void* const* d_in, const int* in_sizes, int n_in,
                              void* d_out, int out_size, void* d_ws, size_t ws_size,
                              hipStream_t stream) {
  const float* x     = (const float*)d_in[0];
  const int*   ei    = (const int*)d_in[1];
  const float* W1    = (const float*)d_in[2];
  const float* b1    = (const float*)d_in[3];
  const float* W2    = (const float*)d_in[4];
  const float* b2    = (const float*)d_in[5];
  const float* gamma = (const float*)d_in[6];
  float* out = (float*)d_out;

  char* ws = (char*)d_ws;
  unsigned short* h1bf = (unsigned short*)(ws + OFF_H1);
  unsigned short* U[2] = {(unsigned short*)(ws + OFF_U0),
                          (unsigned short*)(ws + OFF_U1)};
  unsigned short* w1th = (unsigned short*)(ws + OFF_W1TH);
  unsigned short* w1tl = (unsigned short*)(ws + OFF_W1TL);
  unsigned short* w2th = (unsigned short*)(ws + OFF_W2TH);
  unsigned short* w2tl = (unsigned short*)(ws + OFF_W2TL);
  int*   deg  = (int*)(ws + OFF_DEG);
  float* dis  = (float*)(ws + OFF_DIS);
  int*   rp   = (int*)(ws + OFF_RP);
  int*   cur  = (int*)(ws + OFF_CUR);
  int*   csrc = (int*)(ws + OFF_CSR);
  int*   part = (int*)(ws + OFF_PART);
  int*   offs = (int*)(ws + OFF_OFFS);
  int*   bcnt = (int*)(ws + OFF_BCNT);
  int2*  epk8 = (int2*)(ws + OFF_EPK8);

  hipMemsetAsync(deg, 0, NN * sizeof(int), stream);
  hipMemsetAsync(bcnt, 0, NBKT * sizeof(int), stream);

  // weight prep (tiny)
  k_splitT<<<(INCH * HIDCH + 255) / 256, 256, 0, stream>>>(W1, w1th, w1tl, INCH, HIDCH);
  k_splitT<<<(HIDCH * OUTCH + 255) / 256, 256, 0, stream>>>(W2, w2th, w2tl, HIDCH, OUTCH);

  // graph prep: bucket (+deg), dis, scan, XCD-local fill, pad
  k_bucket<<<(NE + EPB_A - 1) / EPB_A, 256, 0, stream>>>(ei, deg, bcnt, epk8);
  k_dis<<<(NN + 255) / 256, 256, 0, stream>>>(deg, dis, U[0], U[1]);
  k_scan1<<<98, 256, 0, stream>>>(deg, rp, part);
  k_scan2<<<1, 128, 0, stream>>>(part, offs);
  k_scan3<<<98, 256, 0, stream>>>(rp, offs, part, cur);
  k_fill2<<<(BCAP / EPB_B) * NBKT, 256, 0, stream>>>(epk8, bcnt, cur, csrc);
  k_pad<<<(NN + 255) / 256, 256, 0, stream>>>(cur, rp, csrc);

  // MLP
  k_gemm1<<<(NN + 127) / 128, 512, 0, stream>>>(x, w1th, b1, h1bf);
  k_gemm2<<<(NN + 127) / 128, 256, 0, stream>>>(h1bf, w2th, w2tl, b2, gamma, dis,
                                                U[0], out);

  // propagation: 10 hops, full 32-ch rows, gamma accumulated straight into out
  for (int k = 1; k <= KHOPS; ++k) {
    k_hop<<<NN / 16, 256, 0, stream>>>(U[(k - 1) & 1], U[k & 1], out,
                                       rp, csrc, dis, gamma, k);
  }
}

// Round 11
// 523.651 us; speedup vs baseline: 1.1611x; 1.0077x over previous
//
#include <hip/hip_runtime.h>
#include <hip/hip_bf16.h>

#define NN    100000
#define NE    1600000
#define INCH  512
#define HIDCH 256
#define OUTCH 32
#define KHOPS 10
#define NEPAD (NE + 3 * NN)
#define NBKT  8
#define BDIV  12500            // NN / NBKT
#define BCAP  204800           // per-bucket capacity (mean 200K + 11 sigma)
#define EPB_A 8192             // edges per block, bucket phase
#define EPB_B 2048             // edges per block, fill phase

typedef __attribute__((ext_vector_type(8))) short short8;
typedef __attribute__((ext_vector_type(4))) float f32x4;

#define GLOAD_LDS16(gsrc, ldst) \
  __builtin_amdgcn_global_load_lds((const __attribute__((address_space(1))) void*)(gsrc), \
                                   (__attribute__((address_space(3))) void*)(ldst), 16, 0, 0)

// ---------------- workspace layout ----------------
constexpr size_t ws_align(size_t x) { return (x + 255) & ~(size_t)255; }
constexpr size_t USZ = ws_align((size_t)(NN + 1) * 32 * 2);   // one U table (+pad row)
constexpr size_t USH = USZ / 2;                                // stride in ushorts
constexpr size_t OFF_H1    = 0;                                          // [NN][256] bf16
constexpr size_t OFF_U0    = OFF_H1    + ws_align((size_t)NN*HIDCH*2);   // 11 tables u0..u10
constexpr size_t OFF_W1TH  = OFF_U0    + 11 * USZ;                       // [256][512] bf16
constexpr size_t OFF_W1TL  = OFF_W1TH  + ws_align((size_t)HIDCH*INCH*2);
constexpr size_t OFF_W2TH  = OFF_W1TL  + ws_align((size_t)HIDCH*INCH*2); // [32][256] bf16
constexpr size_t OFF_W2TL  = OFF_W2TH  + ws_align((size_t)OUTCH*HIDCH*2);
constexpr size_t OFF_DEG   = OFF_W2TL  + ws_align((size_t)OUTCH*HIDCH*2); // [NN] int
constexpr size_t OFF_DIS   = OFF_DEG   + ws_align((size_t)NN*4);          // [NN] f32
constexpr size_t OFF_RP    = OFF_DIS   + ws_align((size_t)NN*4);          // [NN+1] int (positions)
constexpr size_t OFF_CUR   = OFF_RP    + ws_align((size_t)(NN+1)*4);      // [NN] int (by node)
constexpr size_t OFF_NAP   = OFF_CUR   + ws_align((size_t)NN*4);          // [NN] int node-at-pos
constexpr size_t OFF_POSV  = OFF_NAP   + ws_align((size_t)NN*4);          // [NN] int pos-of-node
constexpr size_t OFF_PDGP  = OFF_POSV  + ws_align((size_t)NN*4);          // [NN] int padded deg at pos
constexpr size_t OFF_D2P   = OFF_PDGP  + ws_align((size_t)NN*4);          // [NN] f32 dis^2 at pos
constexpr size_t OFF_DSQP  = OFF_D2P   + ws_align((size_t)NN*4);          // [NN] f32 sqrt(deg) at pos
constexpr size_t OFF_CSR   = OFF_DSQP  + ws_align((size_t)NN*4);          // [NEPAD] int (pos-translated src)
constexpr size_t OFF_PART  = OFF_CSR   + ws_align((size_t)NEPAD*4);       // [128] int
constexpr size_t OFF_OFFS  = OFF_PART  + ws_align(512);                   // [128] int
constexpr size_t OFF_BCNT  = OFF_OFFS  + ws_align(512);                   // [8] int
constexpr size_t OFF_BINH  = OFF_BCNT  + ws_align(32);                    // [64] int
constexpr size_t OFF_BINO  = OFF_BINH  + ws_align(256);                   // [64] int
constexpr size_t OFF_BINC  = OFF_BINO  + ws_align(256);                   // [64] int
constexpr size_t OFF_EPK8  = OFF_BINC  + ws_align(256);                   // [8][BCAP] int2

// ---------------- bf16 helpers ----------------
__device__ __forceinline__ unsigned short bf16_rne(float f) {
  unsigned int u = __float_as_uint(f);
  u += 0x7fffu + ((u >> 16) & 1u);
  return (unsigned short)(u >> 16);
}
__device__ __forceinline__ float bf16_to_f32(unsigned short h) {
  return __uint_as_float(((unsigned int)h) << 16);
}
__device__ __forceinline__ float bflo(unsigned int w) {
  return __uint_as_float(w << 16);
}
__device__ __forceinline__ float bfhi(unsigned int w) {
  return __uint_as_float(w & 0xffff0000u);
}

// ---------------- phase A: bucket edges by destination range + count deg ----------
__global__ __launch_bounds__(256) void k_bucket(const int* __restrict__ ei,
                                                int* __restrict__ deg,
                                                int* __restrict__ bcnt,
                                                int2* __restrict__ epk8) {
  __shared__ int hist[NBKT], rbase[NBKT], lcur[NBKT];
  const int t = threadIdx.x;
  const int e0 = blockIdx.x * EPB_A;
  if (t < NBKT) hist[t] = 0;
  __syncthreads();
  for (int i = t; i < EPB_A; i += 256) {
    int e = e0 + i;
    if (e < NE) {
      int c = ei[NE + e];
      atomicAdd(&deg[c], 1);
      atomicAdd(&hist[c / BDIV], 1);
    }
  }
  __syncthreads();
  if (t < NBKT) {
    rbase[t] = atomicAdd(&bcnt[t], hist[t]);
    lcur[t] = 0;
  }
  __syncthreads();
  for (int i = t; i < EPB_A; i += 256) {
    int e = e0 + i;
    if (e < NE) {
      int r = ei[e], c = ei[NE + e];
      int b = c / BDIV;
      int slot = atomicAdd(&lcur[b], 1);
      epk8[(size_t)b * BCAP + rbase[b] + slot] = make_int2(r, c);
    }
  }
}

// dis + zero pad row (position NN) of gather-source tables u0..u9
__global__ __launch_bounds__(256) void k_dis(const int* __restrict__ deg,
                                             float* __restrict__ dis,
                                             unsigned short* __restrict__ u0) {
  int v = blockIdx.x * 256 + threadIdx.x;
  if (v < NN) {
    int d = deg[v];
    dis[v] = d > 0 ? rsqrtf((float)d) : 0.0f;
  }
  if (blockIdx.x == 0 && threadIdx.x < 160) {
    int tab = threadIdx.x >> 4, li = threadIdx.x & 15;
    ((unsigned int*)(u0 + (size_t)tab * USH))[(size_t)NN * 16 + li] = 0;
  }
}

// ---------------- degree histogram (64 bins of padded-deg/4) ----------------
__global__ __launch_bounds__(256) void k_hist(const int* __restrict__ deg,
                                              int* __restrict__ binh) {
  __shared__ int h[64];
  const int t = threadIdx.x;
  if (t < 64) h[t] = 0;
  __syncthreads();
  int v = blockIdx.x * 256 + t;
  if (v < NN) {
    int bin = ((deg[v] + 3) & ~3) >> 2;
    if (bin > 63) bin = 63;
    atomicAdd(&h[bin], 1);
  }
  __syncthreads();
  if (t < 64 && h[t]) atomicAdd(&binh[t], h[t]);
}

__global__ __launch_bounds__(64) void k_binscan(const int* __restrict__ binh,
                                                int* __restrict__ bino,
                                                int* __restrict__ binc) {
  __shared__ int s[64];
  int t = threadIdx.x;
  int v = binh[t];
  s[t] = v;
  __syncthreads();
  for (int d = 1; d < 64; d <<= 1) {
    int x = (t >= d) ? s[t - d] : 0;
    __syncthreads();
    s[t] += x;
    __syncthreads();
  }
  bino[t] = s[t] - v;
  binc[t] = s[t] - v;
}

// place nodes into degree-sorted positions (two-level reservation)
__global__ __launch_bounds__(256) void k_place(const int* __restrict__ deg,
                                               int* __restrict__ binc,
                                               int* __restrict__ nap,
                                               int* __restrict__ posv,
                                               int* __restrict__ pdgp) {
  __shared__ int h[64], rb[64], lc[64];
  const int t = threadIdx.x;
  if (t < 64) h[t] = 0;
  __syncthreads();
  int v = blockIdx.x * 256 + t;
  int pdeg = 0, bin = 0;
  bool valid = v < NN;
  if (valid) {
    pdeg = (deg[v] + 3) & ~3;
    bin = pdeg >> 2;
    if (bin > 63) bin = 63;
    atomicAdd(&h[bin], 1);
  }
  __syncthreads();
  if (t < 64) {
    rb[t] = h[t] ? atomicAdd(&binc[t], h[t]) : 0;
    lc[t] = 0;
  }
  __syncthreads();
  if (valid) {
    int slot = atomicAdd(&lc[bin], 1);
    int pos = rb[bin] + slot;
    nap[pos] = v;
    posv[v] = pos;
    pdgp[pos] = pdeg;
  }
}

// ---------------- exclusive scan over pdgp (position-indexed, pre-rounded) --------
__global__ __launch_bounds__(256) void k_scan1(const int* __restrict__ pdgp,
                                               int* __restrict__ rp,
                                               int* __restrict__ part) {
  __shared__ int s[256];
  int b = blockIdx.x, t = threadIdx.x;
  int base = b * 1024 + t * 4;
  int v0 = (base + 0 < NN) ? pdgp[base + 0] : 0;
  int v1 = (base + 1 < NN) ? pdgp[base + 1] : 0;
  int v2 = (base + 2 < NN) ? pdgp[base + 2] : 0;
  int v3 = (base + 3 < NN) ? pdgp[base + 3] : 0;
  int tot = v0 + v1 + v2 + v3;
  s[t] = tot;
  __syncthreads();
  for (int d = 1; d < 256; d <<= 1) {
    int x = (t >= d) ? s[t - d] : 0;
    __syncthreads();
    s[t] += x;
    __syncthreads();
  }
  int excl = s[t] - tot;
  if (t == 255) part[b] = s[255];
  if (base + 0 < NN) rp[base + 0] = excl;
  if (base + 1 < NN) rp[base + 1] = excl + v0;
  if (base + 2 < NN) rp[base + 2] = excl + v0 + v1;
  if (base + 3 < NN) rp[base + 3] = excl + v0 + v1 + v2;
}

__global__ __launch_bounds__(128) void k_scan2(const int* __restrict__ part,
                                               int* __restrict__ offs) {
  __shared__ int s[128];
  int t = threadIdx.x;
  int v = (t < 98) ? part[t] : 0;
  s[t] = v;
  __syncthreads();
  for (int d = 1; d < 128; d <<= 1) {
    int x = (t >= d) ? s[t - d] : 0;
    __syncthreads();
    s[t] += x;
    __syncthreads();
  }
  if (t < 98) offs[t] = s[t] - v;
}

__global__ __launch_bounds__(256) void k_scan3(int* __restrict__ rp,
                                               const int* __restrict__ offs,
                                               const int* __restrict__ part) {
  int b = blockIdx.x, t = threadIdx.x;
  int o = offs[b];
  int base = b * 1024 + t * 4;
#pragma unroll
  for (int j = 0; j < 4; ++j) {
    int i = base + j;
    if (i < NN) rp[i] += o;
  }
  if (b == 0 && t == 0) rp[NN] = offs[97] + part[97];
}

// cur (by node) + per-position dis^2 / sqrt(deg)
__global__ __launch_bounds__(256) void k_curinit(const int* __restrict__ nap,
                                                 const int* __restrict__ rp,
                                                 const int* __restrict__ deg,
                                                 const float* __restrict__ dis,
                                                 int* __restrict__ cur,
                                                 float* __restrict__ d2p,
                                                 float* __restrict__ dsqp) {
  int p = blockIdx.x * 256 + threadIdx.x;
  if (p < NN) {
    int v = nap[p];
    cur[v] = rp[p];
    float dv = dis[v];
    d2p[p] = dv * dv;
    int d = deg[v];
    dsqp[p] = d > 0 ? sqrtf((float)d) : 0.0f;
  }
}

// ---------------- phase B: fill CSR (position-translated src), XCD-matched --------
__global__ __launch_bounds__(256) void k_fill2(const int2* __restrict__ epk8,
                                               const int* __restrict__ bcnt,
                                               const int* __restrict__ posv,
                                               int* __restrict__ cur,
                                               int* __restrict__ csrc) {
  const int bucket = blockIdx.x & 7;
  const int chunk = blockIdx.x >> 3;
  const int cnt = bcnt[bucket];
  const int lo = chunk * EPB_B;
  int n = cnt - lo;
  if (n > EPB_B) n = EPB_B;
  const int2* src = epk8 + (size_t)bucket * BCAP + lo;
  for (int i = threadIdx.x; i < n; i += 256) {
    int2 rc = src[i];
    int p = atomicAdd(&cur[rc.y], 1);
    csrc[p] = posv[rc.x];
  }
}

// pad each position's slots up to rounded length with dummy pos = NN (zero row)
__global__ __launch_bounds__(256) void k_pad(const int* __restrict__ nap,
                                             const int* __restrict__ cur,
                                             const int* __restrict__ rp,
                                             int* __restrict__ csrc) {
  int p = blockIdx.x * 256 + threadIdx.x;
  if (p < NN) {
    int v = nap[p];
    int q = cur[v], e = rp[p + 1];
    for (; q < e; ++q) csrc[q] = NN;
  }
}

// ---------------- split-transpose: dst[n][k] = split(src[k][n]) ----------------
__global__ __launch_bounds__(256) void k_splitT(const float* __restrict__ src,
                                                unsigned short* __restrict__ dh,
                                                unsigned short* __restrict__ dl,
                                                int K, int N) {
  int idx = blockIdx.x * 256 + threadIdx.x;
  if (idx >= K * N) return;
  int n = idx / K, k = idx - n * K;
  float v = src[(size_t)k * N + n];
  unsigned short h = bf16_rne(v);
  dh[idx] = h;
  dl[idx] = bf16_rne(v - bf16_to_f32(h));
}

// ---------------- GEMM1 (r4 pipeline, single product Ah*Bh) -----------------------
__global__ __launch_bounds__(512, 2) void k_gemm1(const float* __restrict__ X,
                                                  const unsigned short* __restrict__ W1Th,
                                                  const float* __restrict__ bias1,
                                                  unsigned short* __restrict__ H1bf) {
  __shared__ __align__(16) unsigned short Ah[2][4096];   // 16 KB
  __shared__ __align__(16) unsigned short Bh[2][8192];   // 32 KB
  const int t = threadIdx.x;
  const int m0 = blockIdx.x * 128;
  const int w = t >> 6, lane = t & 63;
  const int wm = w >> 2, wn = w & 3;

  const int arow = t >> 2;
  const int achk = t & 3;
  int axrow = m0 + arow; if (axrow >= NN) axrow = NN - 1;
  const float* aptr = X + (size_t)axrow * INCH + achk * 8;
  int aidx = (arow >> 4) * 512 + ((arow & 15) + achk * 16) * 8;
  aidx ^= ((aidx >> 7) & 3) << 4;                      // XOR-swizzle (0 conflicts)
  const int aroff = (lane * 8) ^ (((lane >> 4) & 3) << 4);

  const int bn0 = (w * 16) + (lane & 15);
  const int bko = (lane >> 4) * 8;
  const unsigned short* bs0 = W1Th + (size_t)bn0 * INCH + bko;
  const unsigned short* bs1 = W1Th + (size_t)(bn0 + 128) * INCH + bko;

  f32x4 acc[4][4] = {};
  float4 av0, av1;

  av0 = *(const float4*)(aptr);
  av1 = *(const float4*)(aptr + 4);
  GLOAD_LDS16(bs0, &Bh[0][w * 512]);
  GLOAD_LDS16(bs1, &Bh[0][(w + 8) * 512]);
  {
    float af[8] = {av0.x, av0.y, av0.z, av0.w, av1.x, av1.y, av1.z, av1.w};
    short8 ah;
#pragma unroll
    for (int i = 0; i < 8; ++i) {
      unsigned int u = __float_as_uint(af[i]);
      ah[i] = (short)((u + 0x7fffu + ((u >> 16) & 1u)) >> 16);
    }
    *(short8*)&Ah[0][aidx] = ah;
  }
  __syncthreads();

#pragma unroll
  for (int it = 0; it < 16; ++it) {
    const int cur = it & 1, nxt = cur ^ 1;
    const int k0 = it * 32;
    if (it < 15) {
      av0 = *(const float4*)(aptr + k0 + 32);
      av1 = *(const float4*)(aptr + k0 + 36);
      GLOAD_LDS16(bs0 + k0 + 32, &Bh[nxt][w * 512]);
      GLOAD_LDS16(bs1 + k0 + 32, &Bh[nxt][(w + 8) * 512]);
    }
    short8 afrag[4];
#pragma unroll
    for (int mf = 0; mf < 4; ++mf)
      afrag[mf] = *(const short8*)&Ah[cur][(wm * 4 + mf) * 512 + aroff];
#pragma unroll
    for (int nf = 0; nf < 4; ++nf) {
      short8 bfh = *(const short8*)&Bh[cur][(wn * 4 + nf) * 512 + lane * 8];
#pragma unroll
      for (int mf = 0; mf < 4; ++mf) {
        acc[mf][nf] = __builtin_amdgcn_mfma_f32_16x16x32_bf16(afrag[mf], bfh, acc[mf][nf], 0, 0, 0);
      }
    }
    if (it < 15) {
      float af[8] = {av0.x, av0.y, av0.z, av0.w, av1.x, av1.y, av1.z, av1.w};
      short8 ah;
#pragma unroll
      for (int i = 0; i < 8; ++i) {
        unsigned int u = __float_as_uint(af[i]);
        ah[i] = (short)((u + 0x7fffu + ((u >> 16) & 1u)) >> 16);
      }
      *(short8*)&Ah[nxt][aidx] = ah;
    }
    __syncthreads();
  }

  const int colbase = wn * 64 + (lane & 15);
  const int rowbase = m0 + wm * 64 + ((lane >> 4) << 2);
#pragma unroll
  for (int nf = 0; nf < 4; ++nf) {
    int col = colbase + nf * 16;
    float b = bias1[col];
#pragma unroll
    for (int mf = 0; mf < 4; ++mf) {
#pragma unroll
      for (int r = 0; r < 4; ++r) {
        int row = rowbase + mf * 16 + r;
        if (row < NN) {
          float h = fmaxf(acc[mf][nf][r] + b, 0.f);
          H1bf[(size_t)row * HIDCH + col] = bf16_rne(h);
        }
      }
    }
  }
}

// ---------------- GEMM2: h = H1bf @ W2 + b2; u0[pos] = bf16(dis*h); out = g0*h ----
__global__ __launch_bounds__(256) void k_gemm2(const unsigned short* __restrict__ H1bf,
                                               const unsigned short* __restrict__ W2Th,
                                               const unsigned short* __restrict__ W2Tl,
                                               const float* __restrict__ bias2,
                                               const float* __restrict__ gamma,
                                               const float* __restrict__ dis,
                                               const int* __restrict__ posv,
                                               unsigned short* __restrict__ u0,
                                               float* __restrict__ out) {
  __shared__ __align__(16) unsigned short A2[8192];
  __shared__ __align__(16) unsigned short B2h[2048], B2l[2048];
  const int t = threadIdx.x;
  const int m0 = blockIdx.x * 128;

  const int arow = t >> 1;
  int axrow = m0 + arow; if (axrow >= NN) axrow = NN - 1;
  const int akb = (t & 1) * 32;
  const unsigned short* ap = H1bf + (size_t)axrow * HIDCH + akb;
  const int abase = ((arow >> 4) * 2 + (akb >> 5)) * 512 + (arow & 15) * 8;

  const int bnr = t >> 3, bkq = (t & 7) * 8;
  const int bslot = ((bnr >> 4) * 2 + (bkq >> 5)) * 512 +
                    ((bnr & 15) + (((bkq & 31) >> 3) << 4)) * 8;
  const unsigned short* bhp = W2Th + (size_t)bnr * HIDCH + bkq;
  const unsigned short* blp = W2Tl + (size_t)bnr * HIDCH + bkq;

  const int w = t >> 6, lane = t & 63;

  f32x4 acc[2][2] = {};

  for (int k0 = 0; k0 < HIDCH; k0 += 64) {
    uint4 a0 = *(const uint4*)(ap + k0);
    uint4 a1 = *(const uint4*)(ap + k0 + 8);
    uint4 a2 = *(const uint4*)(ap + k0 + 16);
    uint4 a3 = *(const uint4*)(ap + k0 + 24);
    uint4 bh = *(const uint4*)(bhp + k0);
    uint4 bl = *(const uint4*)(blp + k0);

    __syncthreads();

    *(uint4*)&A2[abase + 0 * 128] = a0;
    *(uint4*)&A2[abase + 1 * 128] = a1;
    *(uint4*)&A2[abase + 2 * 128] = a2;
    *(uint4*)&A2[abase + 3 * 128] = a3;
    *(uint4*)&B2h[bslot] = bh;
    *(uint4*)&B2l[bslot] = bl;

    __syncthreads();

    const short8* AV  = (const short8*)A2;
    const short8* BHV = (const short8*)B2h;
    const short8* BLV = (const short8*)B2l;
#pragma unroll
    for (int k32 = 0; k32 < 2; ++k32) {
      short8 bfh[2], bfl[2];
#pragma unroll
      for (int nf = 0; nf < 2; ++nf) {
        bfh[nf] = BHV[(nf * 2 + k32) * 64 + lane];
        bfl[nf] = BLV[(nf * 2 + k32) * 64 + lane];
      }
#pragma unroll
      for (int mf = 0; mf < 2; ++mf) {
        short8 a = AV[((w * 2 + mf) * 2 + k32) * 64 + lane];
#pragma unroll
        for (int nf = 0; nf < 2; ++nf) {
          acc[mf][nf] = __builtin_amdgcn_mfma_f32_16x16x32_bf16(a, bfh[nf], acc[mf][nf], 0, 0, 0);
          acc[mf][nf] = __builtin_amdgcn_mfma_f32_16x16x32_bf16(a, bfl[nf], acc[mf][nf], 0, 0, 0);
        }
      }
    }
  }

  const float g0 = gamma[0];
  const int colb = lane & 15;
  const int rowb = m0 + w * 32 + ((lane >> 4) << 2);
  const float b2c0 = bias2[colb], b2c1 = bias2[16 + colb];
#pragma unroll
  for (int mf = 0; mf < 2; ++mf) {
#pragma unroll
    for (int r = 0; r < 4; ++r) {
      int row = rowb + mf * 16 + r;
      if (row < NN) {
        float dv = dis[row];
        float h0 = acc[mf][0][r] + b2c0;
        float h1 = acc[mf][1][r] + b2c1;
        size_t op = (size_t)posv[row] * 32 + colb;
        u0[op] = bf16_rne(dv * h0);
        u0[op + 16] = bf16_rne(dv * h1);
        size_t o = (size_t)row * 32 + colb;
        out[o] = g0 * h0;
        out[o + 16] = g0 * h1;
      }
    }
  }
}

// ---------------- hop: position-indexed, degree-sorted, no out traffic ------------
// u_k[p] = d2p[p] * sum_{src pos} u_{k-1}[src]; sequential rp/write, balanced waves.
__global__ __launch_bounds__(256) void k_hop(const unsigned short* __restrict__ Uin,
                                             unsigned short* __restrict__ Uout,
                                             const int* __restrict__ rp,
                                             const int* __restrict__ csrc,
                                             const float* __restrict__ d2p) {
  const int t = threadIdx.x;
  const int g = t >> 4;                    // node slot 0..15
  const int li = t & 15;                   // lane in group (2 channels)
  const int p = blockIdx.x * 16 + g;
  const int s = rp[p], e = rp[p + 1];      // multiples of 4 (pads -> pos NN zero row)
  const unsigned int* Uin32 = (const unsigned int*)Uin;

  float ax0 = 0.f, ay0 = 0.f, ax1 = 0.f, ay1 = 0.f;
  float ax2 = 0.f, ay2 = 0.f, ax3 = 0.f, ay3 = 0.f;
  int j = s;
  for (; j + 8 <= e; j += 8) {
    int4 sa = *(const int4*)&csrc[j];      // uniform within group -> broadcast
    int4 sb = *(const int4*)&csrc[j + 4];
    unsigned int w0 = Uin32[(size_t)sa.x * 16 + li];
    unsigned int w1 = Uin32[(size_t)sa.y * 16 + li];
    unsigned int w2 = Uin32[(size_t)sa.z * 16 + li];
    unsigned int w3 = Uin32[(size_t)sa.w * 16 + li];
    unsigned int w4 = Uin32[(size_t)sb.x * 16 + li];
    unsigned int w5 = Uin32[(size_t)sb.y * 16 + li];
    unsigned int w6 = Uin32[(size_t)sb.z * 16 + li];
    unsigned int w7 = Uin32[(size_t)sb.w * 16 + li];
    ax0 += bflo(w0); ay0 += bfhi(w0);
    ax1 += bflo(w1); ay1 += bfhi(w1);
    ax2 += bflo(w2); ay2 += bfhi(w2);
    ax3 += bflo(w3); ay3 += bfhi(w3);
    ax0 += bflo(w4); ay0 += bfhi(w4);
    ax1 += bflo(w5); ay1 += bfhi(w5);
    ax2 += bflo(w6); ay2 += bfhi(w6);
    ax3 += bflo(w7); ay3 += bfhi(w7);
  }
  if (j < e) {
    int4 sa = *(const int4*)&csrc[j];
    unsigned int w0 = Uin32[(size_t)sa.x * 16 + li];
    unsigned int w1 = Uin32[(size_t)sa.y * 16 + li];
    unsigned int w2 = Uin32[(size_t)sa.z * 16 + li];
    unsigned int w3 = Uin32[(size_t)sa.w * 16 + li];
    ax0 += bflo(w0); ay0 += bfhi(w0);
    ax1 += bflo(w1); ay1 += bfhi(w1);
    ax2 += bflo(w2); ay2 += bfhi(w2);
    ax3 += bflo(w3); ay3 += bfhi(w3);
  }
  const float Sx = (ax0 + ax1) + (ax2 + ax3);
  const float Sy = (ay0 + ay1) + (ay2 + ay3);
  const float d2 = d2p[p];
  unsigned int packed = (unsigned int)bf16_rne(d2 * Sx) |
                        ((unsigned int)bf16_rne(d2 * Sy) << 16);
  ((unsigned int*)Uout)[(size_t)p * 16 + li] = packed;
}

// ---------------- merge: out[v] += sum_k gamma_k * sqrt(deg) * u_k[pos] -----------
__global__ __launch_bounds__(256) void k_merge(const unsigned short* __restrict__ u1,
                                               const int* __restrict__ nap,
                                               const float* __restrict__ dsqp,
                                               const float* __restrict__ gamma,
                                               float* __restrict__ out) {
  const int idx = blockIdx.x * 256 + threadIdx.x;   // NN*16 total
  const int p = idx >> 4;
  const int li = idx & 15;
  const int v = nap[p];
  const float f = dsqp[p];
  const size_t o = (size_t)v * 32 + li * 2;
  float2 acc = *(const float2*)&out[o];
#pragma unroll
  for (int k = 0; k < KHOPS; ++k) {
    unsigned int w = ((const unsigned int*)(u1 + (size_t)k * USH))[(size_t)p * 16 + li];
    float gk = gamma[k + 1] * f;
    acc.x = fmaf(gk, bflo(w), acc.x);
    acc.y = fmaf(gk, bfhi(w), acc.y);
  }
  *(float2*)&out[o] = acc;
}

extern "C" void kernel_launch(void* const* d_in, const int* in_sizes, int n_in,
                              void* d_out, int out_size, void* d_ws, size_t ws_size,
                              hipStream_t stream) {
  const float* x     = (const float*)d_in[0];
  const int*   ei    = (const int*)d_in[1];
  const float* W1    = (const float*)d_in[2];
  const float* b1    = (const float*)d_in[3];
  const float* W2    = (const float*)d_in[4];
  const float* b2    = (const float*)d_in[5];
  const float* gamma = (const float*)d_in[6];
  float* out = (float*)d_out;

  char* ws = (char*)d_ws;
  unsigned short* h1bf = (unsigned short*)(ws + OFF_H1);
  unsigned short* u0   = (unsigned short*)(ws + OFF_U0);
  unsigned short* w1th = (unsigned short*)(ws + OFF_W1TH);
  unsigned short* w1tl = (unsigned short*)(ws + OFF_W1TL);
  unsigned short* w2th = (unsigned short*)(ws + OFF_W2TH);
  unsigned short* w2tl = (unsigned short*)(ws + OFF_W2TL);
  int*   deg  = (int*)(ws + OFF_DEG);
  float* dis  = (float*)(ws + OFF_DIS);
  int*   rp   = (int*)(ws + OFF_RP);
  int*   cur  = (int*)(ws + OFF_CUR);
  int*   nap  = (int*)(ws + OFF_NAP);
  int*   posv = (int*)(ws + OFF_POSV);
  int*   pdgp = (int*)(ws + OFF_PDGP);
  float* d2p  = (float*)(ws + OFF_D2P);
  float* dsqp = (float*)(ws + OFF_DSQP);
  int*   csrc = (int*)(ws + OFF_CSR);
  int*   part = (int*)(ws + OFF_PART);
  int*   offs = (int*)(ws + OFF_OFFS);
  int*   bcnt = (int*)(ws + OFF_BCNT);
  int*   binh = (int*)(ws + OFF_BINH);
  int*   bino = (int*)(ws + OFF_BINO);
  int*   binc = (int*)(ws + OFF_BINC);
  int2*  epk8 = (int2*)(ws + OFF_EPK8);

  hipMemsetAsync(deg, 0, NN * sizeof(int), stream);
  hipMemsetAsync(bcnt, 0, NBKT * sizeof(int), stream);
  hipMemsetAsync(binh, 0, 64 * sizeof(int), stream);

  // weight prep (tiny)
  k_splitT<<<(INCH * HIDCH + 255) / 256, 256, 0, stream>>>(W1, w1th, w1tl, INCH, HIDCH);
  k_splitT<<<(HIDCH * OUTCH + 255) / 256, 256, 0, stream>>>(W2, w2th, w2tl, HIDCH, OUTCH);

  // graph prep: bucket (+deg), dis, degree-sort, scan, XCD-local fill, pad
  k_bucket<<<(NE + EPB_A - 1) / EPB_A, 256, 0, stream>>>(ei, deg, bcnt, epk8);
  k_dis<<<(NN + 255) / 256, 256, 0, stream>>>(deg, dis, u0);
  k_hist<<<(NN + 255) / 256, 256, 0, stream>>>(deg, binh);
  k_binscan<<<1, 64, 0, stream>>>(binh, bino, binc);
  k_place<<<(NN + 255) / 256, 256, 0, stream>>>(deg, binc, nap, posv, pdgp);
  k_scan1<<<98, 256, 0, stream>>>(pdgp, rp, part);
  k_scan2<<<1, 128, 0, stream>>>(part, offs);
  k_scan3<<<98, 256, 0, stream>>>(rp, offs, part);
  k_curinit<<<(NN + 255) / 256, 256, 0, stream>>>(nap, rp, deg, dis, cur, d2p, dsqp);
  k_fill2<<<(BCAP / EPB_B) * NBKT, 256, 0, stream>>>(epk8, bcnt, posv, cur, csrc);
  k_pad<<<(NN + 255) / 256, 256, 0, stream>>>(nap, cur, rp, csrc);

  // MLP
  k_gemm1<<<(NN + 127) / 128, 512, 0, stream>>>(x, w1th, b1, h1bf);
  k_gemm2<<<(NN + 127) / 128, 256, 0, stream>>>(h1bf, w2th, w2tl, b2, gamma, dis,
                                                posv, u0, out);

  // propagation: 10 hops into distinct position-indexed tables
  for (int k = 1; k <= KHOPS; ++k) {
    unsigned short* uin  = u0 + (size_t)(k - 1) * USH;
    unsigned short* uout = u0 + (size_t)k * USH;
    k_hop<<<NN / 16, 256, 0, stream>>>(uin, uout, rp, csrc, d2p);
  }

  // final gamma merge
  k_merge<<<NN * 16 / 256, 256, 0, stream>>>(u0 + USH, nap, dsqp, gamma, out);
}

// Round 12
// 511.692 us; speedup vs baseline: 1.1882x; 1.0234x over previous
//
#include <hip/hip_runtime.h>
#include <hip/hip_bf16.h>

#define NN    100000
#define NE    1600000
#define INCH  512
#define HIDCH 256
#define OUTCH 32
#define KHOPS 10
#define NEPAD (NE + 3 * NN)
#define NBKT  8
#define BDIV  12500            // NN / NBKT
#define BCAP  204800           // per-bucket capacity (mean 200K + 11 sigma)
#define EPB_A 8192             // edges per block, bucket phase
#define EPB_B 2048             // edges per block, fill phase

typedef __attribute__((ext_vector_type(8))) short short8;
typedef __attribute__((ext_vector_type(4))) float f32x4;

#define GLOAD_LDS16(gsrc, ldst) \
  __builtin_amdgcn_global_load_lds((const __attribute__((address_space(1))) void*)(gsrc), \
                                   (__attribute__((address_space(3))) void*)(ldst), 16, 0, 0)

// ---------------- workspace layout ----------------
constexpr size_t ws_align(size_t x) { return (x + 255) & ~(size_t)255; }
constexpr size_t USZ = ws_align((size_t)(NN + 1) * 32 * 2);   // one U table (+pad row)
constexpr size_t USH = USZ / 2;                                // stride in ushorts
constexpr size_t OFF_U0    = 0;                                          // 11 tables u0..u10
constexpr size_t OFF_W1TH  = OFF_U0    + 11 * USZ;                       // [256][512] bf16
constexpr size_t OFF_W1TL  = OFF_W1TH  + ws_align((size_t)HIDCH*INCH*2);
constexpr size_t OFF_W2TH  = OFF_W1TL  + ws_align((size_t)HIDCH*INCH*2); // [32][256] bf16
constexpr size_t OFF_W2TL  = OFF_W2TH  + ws_align((size_t)OUTCH*HIDCH*2);
constexpr size_t OFF_DEG   = OFF_W2TL  + ws_align((size_t)OUTCH*HIDCH*2); // [NN] int
constexpr size_t OFF_DIS   = OFF_DEG   + ws_align((size_t)NN*4);          // [NN] f32
constexpr size_t OFF_RP    = OFF_DIS   + ws_align((size_t)NN*4);          // [NN+1] int (positions)
constexpr size_t OFF_CUR   = OFF_RP    + ws_align((size_t)(NN+1)*4);      // [NN] int (by node)
constexpr size_t OFF_NAP   = OFF_CUR   + ws_align((size_t)NN*4);          // [NN] int node-at-pos
constexpr size_t OFF_POSV  = OFF_NAP   + ws_align((size_t)NN*4);          // [NN] int pos-of-node
constexpr size_t OFF_PDGP  = OFF_POSV  + ws_align((size_t)NN*4);          // [NN] int padded deg at pos
constexpr size_t OFF_D2P   = OFF_PDGP  + ws_align((size_t)NN*4);          // [NN] f32 dis^2 at pos
constexpr size_t OFF_DSQP  = OFF_D2P   + ws_align((size_t)NN*4);          // [NN] f32 sqrt(deg) at pos
constexpr size_t OFF_CSR   = OFF_DSQP  + ws_align((size_t)NN*4);          // [NEPAD] int (pos-translated src)
constexpr size_t OFF_PART  = OFF_CSR   + ws_align((size_t)NEPAD*4);       // [128] int
constexpr size_t OFF_OFFS  = OFF_PART  + ws_align(512);                   // [128] int
constexpr size_t OFF_BCNT  = OFF_OFFS  + ws_align(512);                   // [8] int
constexpr size_t OFF_BINH  = OFF_BCNT  + ws_align(32);                    // [64] int
constexpr size_t OFF_BINO  = OFF_BINH  + ws_align(256);                   // [64] int
constexpr size_t OFF_BINC  = OFF_BINO  + ws_align(256);                   // [64] int
constexpr size_t OFF_EPK8  = OFF_BINC  + ws_align(256);                   // [8][BCAP] int2

// ---------------- bf16 helpers ----------------
__device__ __forceinline__ unsigned short bf16_rne(float f) {
  unsigned int u = __float_as_uint(f);
  u += 0x7fffu + ((u >> 16) & 1u);
  return (unsigned short)(u >> 16);
}
__device__ __forceinline__ float bf16_to_f32(unsigned short h) {
  return __uint_as_float(((unsigned int)h) << 16);
}
__device__ __forceinline__ float bflo(unsigned int w) {
  return __uint_as_float(w << 16);
}
__device__ __forceinline__ float bfhi(unsigned int w) {
  return __uint_as_float(w & 0xffff0000u);
}

// ---------------- phase A: bucket edges by destination range + count deg ----------
__global__ __launch_bounds__(256) void k_bucket(const int* __restrict__ ei,
                                                int* __restrict__ deg,
                                                int* __restrict__ bcnt,
                                                int2* __restrict__ epk8) {
  __shared__ int hist[NBKT], rbase[NBKT], lcur[NBKT];
  const int t = threadIdx.x;
  const int e0 = blockIdx.x * EPB_A;
  if (t < NBKT) hist[t] = 0;
  __syncthreads();
  for (int i = t; i < EPB_A; i += 256) {
    int e = e0 + i;
    if (e < NE) {
      int c = ei[NE + e];
      atomicAdd(&deg[c], 1);
      atomicAdd(&hist[c / BDIV], 1);
    }
  }
  __syncthreads();
  if (t < NBKT) {
    rbase[t] = atomicAdd(&bcnt[t], hist[t]);
    lcur[t] = 0;
  }
  __syncthreads();
  for (int i = t; i < EPB_A; i += 256) {
    int e = e0 + i;
    if (e < NE) {
      int r = ei[e], c = ei[NE + e];
      int b = c / BDIV;
      int slot = atomicAdd(&lcur[b], 1);
      epk8[(size_t)b * BCAP + rbase[b] + slot] = make_int2(r, c);
    }
  }
}

// dis + zero pad rows of u0..u9 + degree histogram (fused)
__global__ __launch_bounds__(256) void k_dis(const int* __restrict__ deg,
                                             float* __restrict__ dis,
                                             unsigned short* __restrict__ u0,
                                             int* __restrict__ binh) {
  __shared__ int h[64];
  const int t = threadIdx.x;
  if (t < 64) h[t] = 0;
  __syncthreads();
  int v = blockIdx.x * 256 + t;
  if (v < NN) {
    int d = deg[v];
    dis[v] = d > 0 ? rsqrtf((float)d) : 0.0f;
    int bin = ((d + 3) & ~3) >> 2;
    if (bin > 63) bin = 63;
    atomicAdd(&h[bin], 1);
  }
  __syncthreads();
  if (t < 64 && h[t]) atomicAdd(&binh[t], h[t]);
  if (blockIdx.x == 0 && t < 160) {
    int tab = t >> 4, li = t & 15;
    ((unsigned int*)(u0 + (size_t)tab * USH))[(size_t)NN * 16 + li] = 0;
  }
}

__global__ __launch_bounds__(64) void k_binscan(const int* __restrict__ binh,
                                                int* __restrict__ bino,
                                                int* __restrict__ binc) {
  __shared__ int s[64];
  int t = threadIdx.x;
  int v = binh[t];
  s[t] = v;
  __syncthreads();
  for (int d = 1; d < 64; d <<= 1) {
    int x = (t >= d) ? s[t - d] : 0;
    __syncthreads();
    s[t] += x;
    __syncthreads();
  }
  bino[t] = s[t] - v;
  binc[t] = s[t] - v;
}

// place nodes into degree-sorted positions (two-level reservation)
__global__ __launch_bounds__(256) void k_place(const int* __restrict__ deg,
                                               int* __restrict__ binc,
                                               int* __restrict__ nap,
                                               int* __restrict__ posv,
                                               int* __restrict__ pdgp) {
  __shared__ int h[64], rb[64], lc[64];
  const int t = threadIdx.x;
  if (t < 64) h[t] = 0;
  __syncthreads();
  int v = blockIdx.x * 256 + t;
  int pdeg = 0, bin = 0;
  bool valid = v < NN;
  if (valid) {
    pdeg = (deg[v] + 3) & ~3;
    bin = pdeg >> 2;
    if (bin > 63) bin = 63;
    atomicAdd(&h[bin], 1);
  }
  __syncthreads();
  if (t < 64) {
    rb[t] = h[t] ? atomicAdd(&binc[t], h[t]) : 0;
    lc[t] = 0;
  }
  __syncthreads();
  if (valid) {
    int slot = atomicAdd(&lc[bin], 1);
    int pos = rb[bin] + slot;
    nap[pos] = v;
    posv[v] = pos;
    pdgp[pos] = pdeg;
  }
}

// ---------------- exclusive scan over pdgp ----------------
__global__ __launch_bounds__(256) void k_scan1(const int* __restrict__ pdgp,
                                               int* __restrict__ rp,
                                               int* __restrict__ part) {
  __shared__ int s[256];
  int b = blockIdx.x, t = threadIdx.x;
  int base = b * 1024 + t * 4;
  int v0 = (base + 0 < NN) ? pdgp[base + 0] : 0;
  int v1 = (base + 1 < NN) ? pdgp[base + 1] : 0;
  int v2 = (base + 2 < NN) ? pdgp[base + 2] : 0;
  int v3 = (base + 3 < NN) ? pdgp[base + 3] : 0;
  int tot = v0 + v1 + v2 + v3;
  s[t] = tot;
  __syncthreads();
  for (int d = 1; d < 256; d <<= 1) {
    int x = (t >= d) ? s[t - d] : 0;
    __syncthreads();
    s[t] += x;
    __syncthreads();
  }
  int excl = s[t] - tot;
  if (t == 255) part[b] = s[255];
  if (base + 0 < NN) rp[base + 0] = excl;
  if (base + 1 < NN) rp[base + 1] = excl + v0;
  if (base + 2 < NN) rp[base + 2] = excl + v0 + v1;
  if (base + 3 < NN) rp[base + 3] = excl + v0 + v1 + v2;
}

__global__ __launch_bounds__(128) void k_scan2(const int* __restrict__ part,
                                               int* __restrict__ offs) {
  __shared__ int s[128];
  int t = threadIdx.x;
  int v = (t < 98) ? part[t] : 0;
  s[t] = v;
  __syncthreads();
  for (int d = 1; d < 128; d <<= 1) {
    int x = (t >= d) ? s[t - d] : 0;
    __syncthreads();
    s[t] += x;
    __syncthreads();
  }
  if (t < 98) offs[t] = s[t] - v;
}

__global__ __launch_bounds__(256) void k_scan3(int* __restrict__ rp,
                                               const int* __restrict__ offs,
                                               const int* __restrict__ part) {
  int b = blockIdx.x, t = threadIdx.x;
  int o = offs[b];
  int base = b * 1024 + t * 4;
#pragma unroll
  for (int j = 0; j < 4; ++j) {
    int i = base + j;
    if (i < NN) rp[i] += o;
  }
  if (b == 0 && t == 0) rp[NN] = offs[97] + part[97];
}

// cur (by node) + per-position dis^2 / sqrt(deg)
__global__ __launch_bounds__(256) void k_curinit(const int* __restrict__ nap,
                                                 const int* __restrict__ rp,
                                                 const int* __restrict__ deg,
                                                 const float* __restrict__ dis,
                                                 int* __restrict__ cur,
                                                 float* __restrict__ d2p,
                                                 float* __restrict__ dsqp) {
  int p = blockIdx.x * 256 + threadIdx.x;
  if (p < NN) {
    int v = nap[p];
    cur[v] = rp[p];
    float dv = dis[v];
    d2p[p] = dv * dv;
    int d = deg[v];
    dsqp[p] = d > 0 ? sqrtf((float)d) : 0.0f;
  }
}

// ---------------- phase B: fill CSR (position-translated src), XCD-matched --------
__global__ __launch_bounds__(256) void k_fill2(const int2* __restrict__ epk8,
                                               const int* __restrict__ bcnt,
                                               const int* __restrict__ posv,
                                               int* __restrict__ cur,
                                               int* __restrict__ csrc) {
  const int bucket = blockIdx.x & 7;
  const int chunk = blockIdx.x >> 3;
  const int cnt = bcnt[bucket];
  const int lo = chunk * EPB_B;
  int n = cnt - lo;
  if (n > EPB_B) n = EPB_B;
  const int2* src = epk8 + (size_t)bucket * BCAP + lo;
  for (int i = threadIdx.x; i < n; i += 256) {
    int2 rc = src[i];
    int p = atomicAdd(&cur[rc.y], 1);
    csrc[p] = posv[rc.x];
  }
}

// pad each position's slots up to rounded length with dummy pos = NN (zero row)
__global__ __launch_bounds__(256) void k_pad(const int* __restrict__ nap,
                                             const int* __restrict__ cur,
                                             const int* __restrict__ rp,
                                             int* __restrict__ csrc) {
  int p = blockIdx.x * 256 + threadIdx.x;
  if (p < NN) {
    int v = nap[p];
    int q = cur[v], e = rp[p + 1];
    for (; q < e; ++q) csrc[q] = NN;
  }
}

// ---------------- split-transpose: dst[n][k] = split(src[k][n]) ----------------
__global__ __launch_bounds__(256) void k_splitT(const float* __restrict__ src,
                                                unsigned short* __restrict__ dh,
                                                unsigned short* __restrict__ dl,
                                                int K, int N) {
  int idx = blockIdx.x * 256 + threadIdx.x;
  if (idx >= K * N) return;
  int n = idx / K, k = idx - n * K;
  float v = src[(size_t)k * N + n];
  unsigned short h = bf16_rne(v);
  dh[idx] = h;
  dl[idx] = bf16_rne(v - bf16_to_f32(h));
}

// ---------------- fused MLP: u0[pos]=bf16(dis*h), out=g0*h -------------------------
// Stage 1 (r9 pipeline, unchanged): h1 = relu(X@W1+b1) into registers (128x256/block)
// Stage 2 (fused): h1 -> LDS (two 32KB halves, A-frag layout) ; W2Th (16KB) into the
// A-LDS area via global_load_lds ; in-block GEMM h = h1@W2 + b2 (K=256, 16 MFMA/wave).
__global__ __launch_bounds__(512, 2) void k_mlp(const float* __restrict__ X,
                                                const unsigned short* __restrict__ W1Th,
                                                const float* __restrict__ bias1,
                                                const unsigned short* __restrict__ W2Th,
                                                const float* __restrict__ bias2,
                                                const float* __restrict__ gamma,
                                                const float* __restrict__ dis,
                                                const int* __restrict__ posv,
                                                unsigned short* __restrict__ u0,
                                                float* __restrict__ out) {
  __shared__ __align__(16) unsigned short Ah[2][4096];   // 16 KB (reused: W2 stage)
  __shared__ __align__(16) unsigned short Bh[2][8192];   // 32 KB (reused: h1 halves)
  const int t = threadIdx.x;
  const int m0 = blockIdx.x * 128;
  const int w = t >> 6, lane = t & 63;
  const int wm = w >> 2, wn = w & 3;

  // A staging: thread t -> row t>>2 (0..127), k-chunk t&3 (8 floats)
  const int arow = t >> 2;
  const int achk = t & 3;
  int axrow = m0 + arow; if (axrow >= NN) axrow = NN - 1;
  const float* aptr = X + (size_t)axrow * INCH + achk * 8;
  int aidx = (arow >> 4) * 512 + ((arow & 15) + achk * 16) * 8;
  aidx ^= ((aidx >> 7) & 3) << 4;                      // XOR-swizzle (0 conflicts)
  const int aroff = (lane * 8) ^ (((lane >> 4) & 3) << 4);

  const int bn0 = (w * 16) + (lane & 15);
  const int bko = (lane >> 4) * 8;
  const unsigned short* bs0 = W1Th + (size_t)bn0 * INCH + bko;
  const unsigned short* bs1 = W1Th + (size_t)(bn0 + 128) * INCH + bko;

  f32x4 acc[4][4] = {};
  float4 av0, av1;

  av0 = *(const float4*)(aptr);
  av1 = *(const float4*)(aptr + 4);
  GLOAD_LDS16(bs0, &Bh[0][w * 512]);
  GLOAD_LDS16(bs1, &Bh[0][(w + 8) * 512]);
  {
    float af[8] = {av0.x, av0.y, av0.z, av0.w, av1.x, av1.y, av1.z, av1.w};
    short8 ah;
#pragma unroll
    for (int i = 0; i < 8; ++i) {
      unsigned int u = __float_as_uint(af[i]);
      ah[i] = (short)((u + 0x7fffu + ((u >> 16) & 1u)) >> 16);
    }
    *(short8*)&Ah[0][aidx] = ah;
  }
  __syncthreads();

#pragma unroll
  for (int it = 0; it < 16; ++it) {
    const int cur = it & 1, nxt = cur ^ 1;
    const int k0 = it * 32;
    if (it < 15) {
      av0 = *(const float4*)(aptr + k0 + 32);
      av1 = *(const float4*)(aptr + k0 + 36);
      GLOAD_LDS16(bs0 + k0 + 32, &Bh[nxt][w * 512]);
      GLOAD_LDS16(bs1 + k0 + 32, &Bh[nxt][(w + 8) * 512]);
    }
    short8 afrag[4];
#pragma unroll
    for (int mf = 0; mf < 4; ++mf)
      afrag[mf] = *(const short8*)&Ah[cur][(wm * 4 + mf) * 512 + aroff];
#pragma unroll
    for (int nf = 0; nf < 4; ++nf) {
      short8 bfh = *(const short8*)&Bh[cur][(wn * 4 + nf) * 512 + lane * 8];
#pragma unroll
      for (int mf = 0; mf < 4; ++mf) {
        acc[mf][nf] = __builtin_amdgcn_mfma_f32_16x16x32_bf16(afrag[mf], bfh, acc[mf][nf], 0, 0, 0);
      }
    }
    if (it < 15) {
      float af[8] = {av0.x, av0.y, av0.z, av0.w, av1.x, av1.y, av1.z, av1.w};
      short8 ah;
#pragma unroll
      for (int i = 0; i < 8; ++i) {
        unsigned int u = __float_as_uint(af[i]);
        ah[i] = (short)((u + 0x7fffu + ((u >> 16) & 1u)) >> 16);
      }
      *(short8*)&Ah[nxt][aidx] = ah;
    }
    __syncthreads();
  }

  // ================= fused GEMM2 =================
  unsigned short* AhF = &Ah[0][0];   // 8192 ushorts: W2Th staged here (16 units)
  unsigned short* BhF = &Bh[0][0];   // 16384 ushorts: h1 half (32 units of 512)

  // stage W2Th via gload_lds: unit u = ngrp*8 + k32; wave w does units {2w, 2w+1}
  {
#pragma unroll
    for (int q = 0; q < 2; ++q) {
      int u = w * 2 + q;
      int ngrp = u >> 3, k32 = u & 7;
      const unsigned short* src = W2Th + (size_t)(ngrp * 16 + (lane & 15)) * HIDCH
                                       + k32 * 32 + (lane >> 4) * 8;
      GLOAD_LDS16(src, &AhF[u * 512]);
    }
  }

  const int row15b = (lane >> 4) << 2;
  const int kcol = lane & 15;
  float bset[4];
#pragma unroll
  for (int nf = 0; nf < 4; ++nf) bset[nf] = bias1[wn * 64 + nf * 16 + kcol];

  // ---- half 0: cols 0..127 (waves wn<2 write), compute K=[0,128) ----
  if (wn < 2) {
    const int kbase = wn * 64;
#pragma unroll
    for (int nf = 0; nf < 4; ++nf) {
      int kh = kbase + nf * 16 + kcol;
      int base = ((wm * 4) * 4 + (kh >> 5)) * 512 + ((kh >> 3) & 3) * 128 + (kh & 7);
#pragma unroll
      for (int mf = 0; mf < 4; ++mf) {
#pragma unroll
        for (int r = 0; r < 4; ++r) {
          float h = fmaxf(acc[mf][nf][r] + bset[nf], 0.f);
          BhF[base + mf * 2048 + (row15b + r) * 8] = bf16_rne(h);
        }
      }
    }
  }
  __syncthreads();   // W2 (vmcnt) + h1 half0 (lgkm) ready

  f32x4 acc2[2] = {};
#pragma unroll
  for (int s = 0; s < 4; ++s) {
    short8 a2 = *(const short8*)&BhF[(w * 4 + s) * 512 + lane * 8];
#pragma unroll
    for (int nf = 0; nf < 2; ++nf) {
      short8 bf = *(const short8*)&AhF[(nf * 8 + s) * 512 + lane * 8];
      acc2[nf] = __builtin_amdgcn_mfma_f32_16x16x32_bf16(a2, bf, acc2[nf], 0, 0, 0);
    }
  }
  __syncthreads();   // half0 reads done before overwrite

  // ---- half 1: cols 128..255 (waves wn>=2 write), compute K=[128,256) ----
  if (wn >= 2) {
    const int kbase = (wn - 2) * 64;
#pragma unroll
    for (int nf = 0; nf < 4; ++nf) {
      int kh = kbase + nf * 16 + kcol;
      int base = ((wm * 4) * 4 + (kh >> 5)) * 512 + ((kh >> 3) & 3) * 128 + (kh & 7);
#pragma unroll
      for (int mf = 0; mf < 4; ++mf) {
#pragma unroll
        for (int r = 0; r < 4; ++r) {
          float h = fmaxf(acc[mf][nf][r] + bset[nf], 0.f);
          BhF[base + mf * 2048 + (row15b + r) * 8] = bf16_rne(h);
        }
      }
    }
  }
  __syncthreads();

#pragma unroll
  for (int s = 0; s < 4; ++s) {
    short8 a2 = *(const short8*)&BhF[(w * 4 + s) * 512 + lane * 8];
#pragma unroll
    for (int nf = 0; nf < 2; ++nf) {
      short8 bf = *(const short8*)&AhF[(nf * 8 + 4 + s) * 512 + lane * 8];
      acc2[nf] = __builtin_amdgcn_mfma_f32_16x16x32_bf16(a2, bf, acc2[nf], 0, 0, 0);
    }
  }

  // ---- epilogue: h = acc2 + b2; u0[pos] = bf16(dis*h); out = g0*h ----
  const float g0 = gamma[0];
  const float b2c[2] = {bias2[kcol], bias2[16 + kcol]};
#pragma unroll
  for (int nf = 0; nf < 2; ++nf) {
#pragma unroll
    for (int r = 0; r < 4; ++r) {
      int row = m0 + w * 16 + row15b + r;
      if (row < NN) {
        float h = acc2[nf][r] + b2c[nf];
        float dv = dis[row];
        size_t op = (size_t)posv[row] * 32 + nf * 16 + kcol;
        u0[op] = bf16_rne(dv * h);
        out[(size_t)row * 32 + nf * 16 + kcol] = g0 * h;
      }
    }
  }
}

// ---------------- hop: position-indexed, degree-sorted ----------------------------
__global__ __launch_bounds__(256) void k_hop(const unsigned short* __restrict__ Uin,
                                             unsigned short* __restrict__ Uout,
                                             const int* __restrict__ rp,
                                             const int* __restrict__ csrc,
                                             const float* __restrict__ d2p) {
  const int t = threadIdx.x;
  const int g = t >> 4;                    // node slot 0..15
  const int li = t & 15;                   // lane in group (2 channels)
  const int p = blockIdx.x * 16 + g;
  const int s = rp[p], e = rp[p + 1];      // multiples of 4 (pads -> pos NN zero row)
  const unsigned int* Uin32 = (const unsigned int*)Uin;

  float ax0 = 0.f, ay0 = 0.f, ax1 = 0.f, ay1 = 0.f;
  float ax2 = 0.f, ay2 = 0.f, ax3 = 0.f, ay3 = 0.f;
  int j = s;
  for (; j + 8 <= e; j += 8) {
    int4 sa = *(const int4*)&csrc[j];      // uniform within group -> broadcast
    int4 sb = *(const int4*)&csrc[j + 4];
    unsigned int w0 = Uin32[(size_t)sa.x * 16 + li];
    unsigned int w1 = Uin32[(size_t)sa.y * 16 + li];
    unsigned int w2 = Uin32[(size_t)sa.z * 16 + li];
    unsigned int w3 = Uin32[(size_t)sa.w * 16 + li];
    unsigned int w4 = Uin32[(size_t)sb.x * 16 + li];
    unsigned int w5 = Uin32[(size_t)sb.y * 16 + li];
    unsigned int w6 = Uin32[(size_t)sb.z * 16 + li];
    unsigned int w7 = Uin32[(size_t)sb.w * 16 + li];
    ax0 += bflo(w0); ay0 += bfhi(w0);
    ax1 += bflo(w1); ay1 += bfhi(w1);
    ax2 += bflo(w2); ay2 += bfhi(w2);
    ax3 += bflo(w3); ay3 += bfhi(w3);
    ax0 += bflo(w4); ay0 += bfhi(w4);
    ax1 += bflo(w5); ay1 += bfhi(w5);
    ax2 += bflo(w6); ay2 += bfhi(w6);
    ax3 += bflo(w7); ay3 += bfhi(w7);
  }
  if (j < e) {
    int4 sa = *(const int4*)&csrc[j];
    unsigned int w0 = Uin32[(size_t)sa.x * 16 + li];
    unsigned int w1 = Uin32[(size_t)sa.y * 16 + li];
    unsigned int w2 = Uin32[(size_t)sa.z * 16 + li];
    unsigned int w3 = Uin32[(size_t)sa.w * 16 + li];
    ax0 += bflo(w0); ay0 += bfhi(w0);
    ax1 += bflo(w1); ay1 += bfhi(w1);
    ax2 += bflo(w2); ay2 += bfhi(w2);
    ax3 += bflo(w3); ay3 += bfhi(w3);
  }
  const float Sx = (ax0 + ax1) + (ax2 + ax3);
  const float Sy = (ay0 + ay1) + (ay2 + ay3);
  const float d2 = d2p[p];
  unsigned int packed = (unsigned int)bf16_rne(d2 * Sx) |
                        ((unsigned int)bf16_rne(d2 * Sy) << 16);
  ((unsigned int*)Uout)[(size_t)p * 16 + li] = packed;
}

// ---------------- merge: out[v] += sum_k gamma_k * sqrt(deg) * u_k[pos] -----------
__global__ __launch_bounds__(256) void k_merge(const unsigned short* __restrict__ u1,
                                               const int* __restrict__ nap,
                                               const float* __restrict__ dsqp,
                                               const float* __restrict__ gamma,
                                               float* __restrict__ out) {
  const int idx = blockIdx.x * 256 + threadIdx.x;   // NN*16 total
  const int p = idx >> 4;
  const int li = idx & 15;
  const int v = nap[p];
  const float f = dsqp[p];
  const size_t o = (size_t)v * 32 + li * 2;
  float2 acc = *(const float2*)&out[o];
#pragma unroll
  for (int k = 0; k < KHOPS; ++k) {
    unsigned int w = ((const unsigned int*)(u1 + (size_t)k * USH))[(size_t)p * 16 + li];
    float gk = gamma[k + 1] * f;
    acc.x = fmaf(gk, bflo(w), acc.x);
    acc.y = fmaf(gk, bfhi(w), acc.y);
  }
  *(float2*)&out[o] = acc;
}

extern "C" void kernel_launch(void* const* d_in, const int* in_sizes, int n_in,
                              void* d_out, int out_size, void* d_ws, size_t ws_size,
                              hipStream_t stream) {
  const float* x     = (const float*)d_in[0];
  const int*   ei    = (const int*)d_in[1];
  const float* W1    = (const float*)d_in[2];
  const float* b1    = (const float*)d_in[3];
  const float* W2    = (const float*)d_in[4];
  const float* b2    = (const float*)d_in[5];
  const float* gamma = (const float*)d_in[6];
  float* out = (float*)d_out;

  char* ws = (char*)d_ws;
  unsigned short* u0   = (unsigned short*)(ws + OFF_U0);
  unsigned short* w1th = (unsigned short*)(ws + OFF_W1TH);
  unsigned short* w1tl = (unsigned short*)(ws + OFF_W1TL);
  unsigned short* w2th = (unsigned short*)(ws + OFF_W2TH);
  unsigned short* w2tl = (unsigned short*)(ws + OFF_W2TL);
  int*   deg  = (int*)(ws + OFF_DEG);
  float* dis  = (float*)(ws + OFF_DIS);
  int*   rp   = (int*)(ws + OFF_RP);
  int*   cur  = (int*)(ws + OFF_CUR);
  int*   nap  = (int*)(ws + OFF_NAP);
  int*   posv = (int*)(ws + OFF_POSV);
  int*   pdgp = (int*)(ws + OFF_PDGP);
  float* d2p  = (float*)(ws + OFF_D2P);
  float* dsqp = (float*)(ws + OFF_DSQP);
  int*   csrc = (int*)(ws + OFF_CSR);
  int*   part = (int*)(ws + OFF_PART);
  int*   offs = (int*)(ws + OFF_OFFS);
  int*   bcnt = (int*)(ws + OFF_BCNT);
  int*   binh = (int*)(ws + OFF_BINH);
  int*   bino = (int*)(ws + OFF_BINO);
  int*   binc = (int*)(ws + OFF_BINC);
  int2*  epk8 = (int2*)(ws + OFF_EPK8);

  hipMemsetAsync(deg, 0, NN * sizeof(int), stream);
  hipMemsetAsync(bcnt, 0, NBKT * sizeof(int), stream);
  hipMemsetAsync(binh, 0, 64 * sizeof(int), stream);

  // weight prep (tiny)
  k_splitT<<<(INCH * HIDCH + 255) / 256, 256, 0, stream>>>(W1, w1th, w1tl, INCH, HIDCH);
  k_splitT<<<(HIDCH * OUTCH + 255) / 256, 256, 0, stream>>>(W2, w2th, w2tl, HIDCH, OUTCH);

  // graph prep: bucket (+deg), dis(+hist), degree-sort, scan, XCD-local fill, pad
  k_bucket<<<(NE + EPB_A - 1) / EPB_A, 256, 0, stream>>>(ei, deg, bcnt, epk8);
  k_dis<<<(NN + 255) / 256, 256, 0, stream>>>(deg, dis, u0, binh);
  k_binscan<<<1, 64, 0, stream>>>(binh, bino, binc);
  k_place<<<(NN + 255) / 256, 256, 0, stream>>>(deg, binc, nap, posv, pdgp);
  k_scan1<<<98, 256, 0, stream>>>(pdgp, rp, part);
  k_scan2<<<1, 128, 0, stream>>>(part, offs);
  k_scan3<<<98, 256, 0, stream>>>(rp, offs, part);
  k_curinit<<<(NN + 255) / 256, 256, 0, stream>>>(nap, rp, deg, dis, cur, d2p, dsqp);
  k_fill2<<<(BCAP / EPB_B) * NBKT, 256, 0, stream>>>(epk8, bcnt, posv, cur, csrc);
  k_pad<<<(NN + 255) / 256, 256, 0, stream>>>(nap, cur, rp, csrc);

  // fused MLP (gemm1 + gemm2): writes u0[pos] and out = g0*h
  k_mlp<<<(NN + 127) / 128, 512, 0, stream>>>(x, w1th, b1, w2th, b2, gamma, dis,
                                              posv, u0, out);

  // propagation: 10 hops into distinct position-indexed tables
  for (int k = 1; k <= KHOPS; ++k) {
    unsigned short* uin  = u0 + (size_t)(k - 1) * USH;
    unsigned short* uout = u0 + (size_t)k * USH;
    k_hop<<<NN / 16, 256, 0, stream>>>(uin, uout, rp, csrc, d2p);
  }

  // final gamma merge
  k_merge<<<NN * 16 / 256, 256, 0, stream>>>(u0 + USH, nap, dsqp, gamma, out);
}